// Round 14
// baseline (1150.594 us; speedup 1.0000x reference)
//
#include <hip/hip_runtime.h>
#include <math.h>

typedef float f4 __attribute__((ext_vector_type(4)));
typedef f4 f4u __attribute__((aligned(4)));   // 4B-aligned vector load
typedef float f32x4 __attribute__((ext_vector_type(4)));
typedef short short8 __attribute__((ext_vector_type(8)));

constexpr int NB  = 8;
constexpr int NN  = 512;
constexpr int NC  = 256;
constexpr int NHW = 49;
constexpr int NM  = NB * NN;   // 4096
constexpr int XS  = 260;       // k_prep transposed x row stride (floats)

// ---- workspace layout (float offsets) ----
constexpr size_t WS_SMEAN = 0;                        // 8*256              -> 2048
constexpr size_t WS_YST   = 2048;                     // 8*256*49           -> 102400
constexpr size_t WS_UST   = 102400;                   // 8*64*49            -> 127488
constexpr size_t WS_WFH   = 127488;                   // 20*8*64*8 bf16     -> 168448
constexpr size_t WS_WFL   = 168448;                   // same (lo part)     -> 209408
constexpr size_t WS_NMS   = 209408;                   // NMS scratch below
constexpr size_t WS_SBOX  = WS_NMS;                   // 8*512*4
constexpr size_t WS_SAREA = WS_SBOX + 16384;          // 4096
constexpr size_t WS_SIDX  = WS_SAREA + 4096;          // 4096 (ints)
constexpr size_t WS_MASK  = WS_SIDX + 4096;           // 8*512 u64x8 = 65536 floats

// ---- output layout (floats): boxes[4096*4] | scores[4096] | keep[4096] ----
constexpr size_t OUT_SCORES = (size_t)NM * 4;
constexpr size_t OUT_KEEP   = OUT_SCORES + NM;

__device__ __forceinline__ unsigned short bf16_rne(float f) {
    unsigned u = __float_as_uint(f);
    return (unsigned short)((u + 0x7FFFu + ((u >> 16) & 1u)) >> 16);
}
__device__ __forceinline__ float bf16_to_f(unsigned short h) {
    return __uint_as_float(((unsigned)h) << 16);
}

// stage x [256][49] (global) -> LDS transposed [49][XS] f32 (k_prep only)
__device__ __forceinline__ void stage_xT(const float* __restrict__ g, float* sx, int t) {
#pragma unroll
    for (int rep = 0; rep < 13; ++rep) {
        int id = rep * 256 + t;
        if (id < 3136) {
            int c4 = id / 49;
            int hw = id - c4 * 49;
            f4 v;
            v[0] = g[(c4 * 4 + 0) * 49 + hw];
            v[1] = g[(c4 * 4 + 1) * 49 + hw];
            v[2] = g[(c4 * 4 + 2) * 49 + hw];
            v[3] = g[(c4 * 4 + 3) * 49 + hw];
            *(f4*)&sx[hw * XS + c4 * 4] = v;
        }
    }
}

// ---------------------------------------------------------------------------
// K1: merged prep. grid = 104, block = 256.
//  blocks 0..63  : per-batch precompute (b = blk>>3, og8 = blk&7: 32 y_s rows
//                  each; og8<2 also 32 u_s rows; og8==0 also smean).
//  blocks 64..103: split-bf16 A-fragment build (4 old 64-lane blocks each).
// ---------------------------------------------------------------------------
__global__ __launch_bounds__(256, 2) void k_prep(
    const float* __restrict__ bfs, const float* __restrict__ Wcor,
    const float* __restrict__ W1, float* __restrict__ ws)
{
    int t = threadIdx.x, blk = blockIdx.x;

    if (blk >= 64) {
        // ---- A-fragment build: old k_wfrag blocks (blk-64)*4 + (t>>6) ----
        int ob = (blk - 64) * 4 + (t >> 6);    // 0..159
        int l = t & 63;
        int mt = ob >> 3, ks = ob & 7;
        int row = mt * 16 + (l & 15);
        int k0 = ks * 32 + (l >> 4) * 8;
        const float* src = (row < 256) ? (Wcor + (size_t)row * 256 + k0)
                                       : (W1 + (size_t)(row - 256) * 512 + k0);
        short hv[8], lv[8];
#pragma unroll
        for (int j = 0; j < 8; ++j) {
            float v = src[j];
            unsigned short hh = bf16_rne(v);
            unsigned short hl = bf16_rne(v - bf16_to_f(hh));
            hv[j] = (short)hh; lv[j] = (short)hl;
        }
        short* dh = (short*)(ws + WS_WFH) + ((size_t)ob * 64 + l) * 8;
        short* dl = (short*)(ws + WS_WFL) + ((size_t)ob * 64 + l) * 8;
#pragma unroll
        for (int j = 0; j < 8; ++j) { dh[j] = hv[j]; dl[j] = lv[j]; }
        return;
    }

    __shared__ __align__(16) float smem[49 * XS + 16];
    float* sx = smem;
    int b = blk >> 3;
    int og8 = blk & 7;

    stage_xT(bfs + (size_t)b * 12544, sx, t);
    __syncthreads();

    if (og8 == 0) {
        float s = 0.f;
        for (int hw = 0; hw < 49; ++hw) s += sx[hw * XS + t];
        ws[WS_SMEAN + (size_t)b * 256 + t] = s * (1.f / 49.f);
    }

    int og2 = t >> 3, hwg = t & 7;       // og2: 0..31, one y_s row each
    int hwb = (hwg == 7) ? 0 : hwg * 7;
    int oA = og8 * 32 + og2;
    bool do_u = (og8 < 2);
    int o2 = og8 * 32 + og2;             // u_s row (valid when do_u)

    float acc0[7] = {0,0,0,0,0,0,0};
    float a1a[7]  = {0,0,0,0,0,0,0};
    const float* xrow = sx + hwb * XS;
    const float* w0r = Wcor + (size_t)oA * 256;
    const float* war = W1 + (size_t)o2 * 512 + 256;   // s-part

#pragma unroll 1
    for (int c4 = 0; c4 < 64; ++c4) {
        f4 xv[7];
#pragma unroll
        for (int i = 0; i < 7; ++i) xv[i] = *(const f4*)&xrow[i * XS + c4 * 4];
        f4 w0 = *(const f4*)&w0r[c4 * 4];
        f4 wa = *(const f4*)&war[c4 * 4];
#pragma unroll
        for (int j = 0; j < 4; ++j) {
#pragma unroll
            for (int i = 0; i < 7; ++i) {
                float x = xv[i][j];
                acc0[i] = fmaf(w0[j], x, acc0[i]);
                a1a[i]  = fmaf(wa[j], x, a1a[i]);
            }
        }
    }

    if (hwg < 7) {
#pragma unroll
        for (int i = 0; i < 7; ++i) {
            int hw = hwb + i;
            ws[WS_YST + ((size_t)b * 256 + oA) * 49 + hw] = acc0[i];
            if (do_u)
                ws[WS_UST + ((size_t)b * 64 + o2) * 49 + hw] = a1a[i];
        }
    }
}

// ---------------------------------------------------------------------------
// K2: heavy per-m kernel. MFMA fused K-loop + broadcast-conv phase 2 +
// FUSED FC PATH (round 14): q_mean kept in-register, xfc/h staged in dead
// LDS after W3, score_fc folded into the merged block reduction; this kernel
// now emits the COMPLETE sigmoid score (k_fc deleted).
// 3 blocks/CU (50.7 KB LDS; 4 blocks is VGPR-infeasible: acc 80 + ~70 > 128).
// ---------------------------------------------------------------------------
__global__ __launch_bounds__(256, 3) void k_heavy(
    const float* __restrict__ bfq,
    const float* __restrict__ W2, const float* __restrict__ W3,
    const float* __restrict__ scor_w, const float* __restrict__ scor_b,
    const float* __restrict__ spr_w, const float* __restrict__ spr_b,
    const float* __restrict__ dpr_w, const float* __restrict__ dpr_b,
    const float* __restrict__ fc1_w, const float* __restrict__ fc1_b,
    const float* __restrict__ fc2_w, const float* __restrict__ fc2_b,
    const float* __restrict__ sfc_w, const float* __restrict__ sfc_b,
    const float* __restrict__ proposals, const int* __restrict__ image_size,
    float* __restrict__ ws, float* __restrict__ out)
{
    __shared__ __align__(16) short xh[49 * 256];   // 24.5 KiB
    __shared__ __align__(16) short xl[49 * 256];   // 24.5 KiB
    __shared__ float red[20];

    int t = threadIdx.x, m = blockIdx.x, b = m >> 9;
    const float* xg = bfq + (size_t)m * 12544 + (size_t)t * 49;

    // ---- stage x -> bf16 hi AND lo (all 13 loads issued unrolled) ----
    float q_sum = 0.f;                 // q_mean numerator, kept in-register
    {
#pragma unroll
        for (int r = 0; r < 12; ++r) {
            f4u v = *(const f4u*)&xg[r * 4];
#pragma unroll
            for (int j = 0; j < 4; ++j) {
                int hw = r * 4 + j;
                float x = v[j];
                q_sum += x;
                unsigned short hh = bf16_rne(x);
                int idx = (hw * 256 + t) ^ ((hw & 7) << 3);
                xh[idx] = (short)hh;
                xl[idx] = (short)bf16_rne(x - bf16_to_f(hh));
            }
        }
        float x48 = xg[48];
        q_sum += x48;
        unsigned short hh48 = bf16_rne(x48);
        xh[48 * 256 + t] = (short)hh48;            // 48&7 == 0 -> no xor
        xl[48 * 256 + t] = (short)bf16_rne(x48 - bf16_to_f(hh48));
    }
    __syncthreads();

    int w = t >> 6, l = t & 63, cl = l & 15, g = l >> 4;

    f32x4 acc[5][4];
#pragma unroll
    for (int i = 0; i < 5; ++i)
#pragma unroll
        for (int nt = 0; nt < 4; ++nt) acc[i][nt] = (f32x4)0.f;

    const short* wfH = (const short*)(ws + WS_WFH);
    const short* wfL = (const short*)(ws + WS_WFL);

    // precompute the 4 clamped B-column base offsets (col>=49 -> col 0)
    int bcol[4];
#pragma unroll
    for (int nt = 0; nt < 4; ++nt) {
        int col = nt * 16 + cl;
        if (col >= 49) col = 0;
        bcol[nt] = col;
    }

    // ---- fused K-loop: acc += Wh*xh + Wh*xl + Wl*xh ----
#pragma unroll 1
    for (int ks = 0; ks < 8; ++ks) {
        short8 bh[4], bl[4];
#pragma unroll
        for (int nt = 0; nt < 4; ++nt) {
            int col = bcol[nt];
            int idx = (col * 256 + ks * 32 + g * 8) ^ ((col & 7) << 3);
            bh[nt] = *(const short8*)&xh[idx];
            bl[nt] = *(const short8*)&xl[idx];
        }
#pragma unroll
        for (int i = 0; i < 5; ++i) {
            int mt = w + 4 * i;
            size_t off = ((size_t)(mt * 8 + ks) * 64 + l) * 8;
            short8 ah = *(const short8*)&wfH[off];
            short8 al = *(const short8*)&wfL[off];
            acc[i][0] = __builtin_amdgcn_mfma_f32_16x16x32_bf16(ah, bh[0], acc[i][0], 0, 0, 0);
            acc[i][1] = __builtin_amdgcn_mfma_f32_16x16x32_bf16(ah, bh[1], acc[i][1], 0, 0, 0);
            acc[i][2] = __builtin_amdgcn_mfma_f32_16x16x32_bf16(ah, bh[2], acc[i][2], 0, 0, 0);
            acc[i][3] = __builtin_amdgcn_mfma_f32_16x16x32_bf16(ah, bh[3], acc[i][3], 0, 0, 0);
            acc[i][0] = __builtin_amdgcn_mfma_f32_16x16x32_bf16(ah, bl[0], acc[i][0], 0, 0, 0);
            acc[i][1] = __builtin_amdgcn_mfma_f32_16x16x32_bf16(ah, bl[1], acc[i][1], 0, 0, 0);
            acc[i][2] = __builtin_amdgcn_mfma_f32_16x16x32_bf16(ah, bl[2], acc[i][2], 0, 0, 0);
            acc[i][3] = __builtin_amdgcn_mfma_f32_16x16x32_bf16(ah, bl[3], acc[i][3], 0, 0, 0);
            acc[i][0] = __builtin_amdgcn_mfma_f32_16x16x32_bf16(al, bh[0], acc[i][0], 0, 0, 0);
            acc[i][1] = __builtin_amdgcn_mfma_f32_16x16x32_bf16(al, bh[1], acc[i][1], 0, 0, 0);
            acc[i][2] = __builtin_amdgcn_mfma_f32_16x16x32_bf16(al, bh[2], acc[i][2], 0, 0, 0);
            acc[i][3] = __builtin_amdgcn_mfma_f32_16x16x32_bf16(al, bh[3], acc[i][3], 0, 0, 0);
        }
    }

    // ---- corr epilogue: tiles w,w+4,w+8,w+12 = Wcor rows (<256).
    // C/D layout (m89): col = lane&15, row_in_tile = (lane>>4)*4 + reg.
    float csum = 0.f;
    {
        const float* yb = ws + WS_YST + (size_t)b * 256 * 49;
#pragma unroll
        for (int i = 0; i < 4; ++i) {
            int row0 = (w + 4 * i) * 16 + g * 4;
#pragma unroll
            for (int q = 0; q < 4; ++q) {
                int row = row0 + q;
                float p = 0.f;
#pragma unroll
                for (int nt = 0; nt < 4; ++nt) {
                    int col = nt * 16 + cl;
                    if (col < 49) p += acc[i][nt][q] * yb[(size_t)row * 49 + col];
                }
                p += __shfl_xor(p, 1, 64);
                p += __shfl_xor(p, 2, 64);
                p += __shfl_xor(p, 4, 64);
                p += __shfl_xor(p, 8, 64);
                if (cl == 0) csum += fmaxf(p, 0.f) * scor_w[row];
            }
        }
    }
    __syncthreads();   // ALL waves done with MFMA B-reads; xh/xl reusable

    // ---- x1 epilogue: tile w+16 = W1q rows; write s1[64][52] over xh ----
    float* s1    = (float*)xh;                 // [64][52]   3328 floats
    float* sp1   = s1 + 64 * 52;               // [64][28]   1792 -> 5120 <= 6272
    float* cpart = (float*)xl;                 // [4][64][11] 2816 floats
    float* sc2T  = cpart + 2816;               // [9][64]     576 -> 3392 <= 6272
    {
        const float* ub = ws + WS_UST + (size_t)b * 64 * 49;
        int ch0 = w * 16 + g * 4;
#pragma unroll
        for (int q = 0; q < 4; ++q) {
            int ch = ch0 + q;
#pragma unroll
            for (int nt = 0; nt < 4; ++nt) {
                int col = nt * 16 + cl;
                if (col < 49)
                    s1[ch * 52 + col] = fmaxf(acc[4][nt][q] + ub[(size_t)ch * 49 + col], 0.f);
            }
        }
    }
    __syncthreads();

    // ---- avgpool3 7x7 -> 5x5, padded [64][28] ----
    for (int i = t; i < 64 * 25; i += 256) {
        int ch = i / 25, pos = i - ch * 25;
        int py = pos / 5, px = pos - py * 5;
        const float* base = s1 + ch * 52 + py * 7 + px;
        float s = base[0] + base[1] + base[2]
                + base[7] + base[8] + base[9]
                + base[14] + base[15] + base[16];
        sp1[ch * 28 + pos] = s * (1.f / 9.f);
    }
    __syncthreads();

    // ---- conv3x3 VALID 64->64, thread = (oc, icq=wave) ----
    // Activation reads: wave-uniform broadcast f4's. Weights: coalesced f4u.
    {
        int oc = t & 63, icq = t >> 6;
        float a9[9] = {0,0,0,0,0,0,0,0,0};
        const float* wb2 = W2 + (size_t)oc * 576 + icq * 16 * 9;
#pragma unroll 1
        for (int ic16 = 0; ic16 < 16; ++ic16) {
            int ic = icq * 16 + ic16;
            const f4* ar = (const f4*)(sp1 + ic * 28);
            float av[28];
            *(f4*)&av[0]  = ar[0];
            *(f4*)&av[4]  = ar[1];
            *(f4*)&av[8]  = ar[2];
            *(f4*)&av[12] = ar[3];
            *(f4*)&av[16] = ar[4];
            *(f4*)&av[20] = ar[5];
            *(f4*)&av[24] = ar[6];
            const float* wi = wb2 + ic16 * 9;
            f4u w0 = *(const f4u*)wi;
            f4u w1 = *(const f4u*)(wi + 4);
            float wv[9] = { w0[0], w0[1], w0[2], w0[3], w1[0], w1[1], w1[2], w1[3], wi[8] };
#pragma unroll
            for (int py = 0; py < 3; ++py)
#pragma unroll
                for (int px = 0; px < 3; ++px) {
                    int p9 = py * 3 + px;
#pragma unroll
                    for (int ky = 0; ky < 3; ++ky)
#pragma unroll
                        for (int kx = 0; kx < 3; ++kx)
                            a9[p9] = fmaf(wv[ky * 3 + kx],
                                          av[(py + ky) * 5 + (px + kx)], a9[p9]);
                }
        }
#pragma unroll
        for (int p = 0; p < 9; ++p)
            cpart[((size_t)icq * 64 + oc) * 11 + p] = a9[p];
    }
    __syncthreads();

    // combine 4 partials + relu -> sc2T[pos][oc]
    for (int i = t; i < 576; i += 256) {
        int pos = i >> 6, occ = i & 63;
        float s = cpart[((size_t)0 * 64 + occ) * 11 + pos]
                + cpart[((size_t)1 * 64 + occ) * 11 + pos]
                + cpart[((size_t)2 * 64 + occ) * 11 + pos]
                + cpart[((size_t)3 * 64 + occ) * 11 + pos];
        sc2T[pos * 64 + occ] = fmaxf(s, 0.f);
    }
    __syncthreads();

    // ---- W3 (256x64) + relu + avgpool3 3x3 -> 1 (broadcast f4 reads) ----
    float xfin;
    {
        float xw[9] = {0,0,0,0,0,0,0,0,0};
        const f4* wr = (const f4*)(W3 + (size_t)t * 64);
#pragma unroll 1
        for (int gg = 0; gg < 16; ++gg) {
            f4 wv4 = wr[gg];
#pragma unroll
            for (int p = 0; p < 9; ++p) {
                f4 c = *(const f4*)(sc2T + p * 64 + gg * 4);
                xw[p] = fmaf(wv4[0], c[0], xw[p]);
                xw[p] = fmaf(wv4[1], c[1], xw[p]);
                xw[p] = fmaf(wv4[2], c[2], xw[p]);
                xw[p] = fmaf(wv4[3], c[3], xw[p]);
            }
        }
        float s = 0.f;
#pragma unroll
        for (int p = 0; p < 9; ++p) s += fmaxf(xw[p], 0.f);
        xfin = s * (1.f / 9.f);
    }

    // ---- fused FC path (s1 region is dead: pool/conv/W3 all consumed) ----
    float* xfc  = s1;            // [512]
    float* hbuf = s1 + 512;      // [256]
    xfc[t]       = q_sum * (1.f / 49.f);
    xfc[256 + t] = ws[WS_SMEAN + (size_t)b * 256 + t];
    __syncthreads();

    float fcval;
    {
        const f4* wr = (const f4*)(fc1_w + (size_t)t * 512);
        float a = 0.f;
#pragma unroll 1
        for (int k4 = 0; k4 < 128; ++k4) {
            f4 wv = wr[k4];
            f4 xv = *(const f4*)&xfc[k4 * 4];
            a = fmaf(wv[0], xv[0], a);
            a = fmaf(wv[1], xv[1], a);
            a = fmaf(wv[2], xv[2], a);
            a = fmaf(wv[3], xv[3], a);
        }
        hbuf[t] = fmaxf(a + fc1_b[t], 0.f);
    }
    __syncthreads();
    {
        const f4* wr = (const f4*)(fc2_w + (size_t)t * 256);
        float a = 0.f;
#pragma unroll 1
        for (int k4 = 0; k4 < 64; ++k4) {
            f4 wv = wr[k4];
            f4 xv = *(const f4*)&hbuf[k4 * 4];
            a = fmaf(wv[0], xv[0], a);
            a = fmaf(wv[1], xv[1], a);
            a = fmaf(wv[2], xv[2], a);
            a = fmaf(wv[3], xv[3], a);
        }
        fcval = sfc_w[t] * fmaxf(a + fc2_b[t], 0.f);
    }

    // ---- merged 5-way block reduction: ONE barrier (v0 carries pr+cor+fc) --
    float v0 = xfin * spr_w[t] + csum + fcval;
    float v1 = xfin * dpr_w[0 * 256 + t];
    float v2 = xfin * dpr_w[1 * 256 + t];
    float v3 = xfin * dpr_w[2 * 256 + t];
    float v4 = xfin * dpr_w[3 * 256 + t];
#pragma unroll
    for (int off = 32; off > 0; off >>= 1) {
        v0 += __shfl_xor(v0, off, 64);
        v1 += __shfl_xor(v1, off, 64);
        v2 += __shfl_xor(v2, off, 64);
        v3 += __shfl_xor(v3, off, 64);
        v4 += __shfl_xor(v4, off, 64);
    }
    if (l == 0) {
        red[w * 5 + 0] = v0; red[w * 5 + 1] = v1; red[w * 5 + 2] = v2;
        red[w * 5 + 3] = v3; red[w * 5 + 4] = v4;
    }
    __syncthreads();

    if (t == 0) {
        float r_s  = red[0] + red[5] + red[10] + red[15];
        float r_d0 = red[1] + red[6] + red[11] + red[16];
        float r_d1 = red[2] + red[7] + red[12] + red[17];
        float r_d2 = red[3] + red[8] + red[13] + red[18];
        float r_d3 = red[4] + red[9] + red[14] + red[19];

        float tot = r_s + spr_b[0] + scor_b[0] + sfc_b[0];
        out[OUT_SCORES + m] = 1.0f / (1.0f + expf(-tot));

        float d0 = r_d0 + dpr_b[0];
        float d1 = r_d1 + dpr_b[1];
        float d2 = fminf(r_d2 + dpr_b[2], 4.135166556742356f);
        float d3 = fminf(r_d3 + dpr_b[3], 4.135166556742356f);

        const float* pr = proposals + (size_t)m * 4;
        float x1p = pr[0], y1p = pr[1], x2p = pr[2], y2p = pr[3];
        float wd = x2p - x1p, hd = y2p - y1p;
        float cx = x1p + 0.5f * wd, cy = y1p + 0.5f * hd;
        float pcx = d0 * wd + cx, pcy = d1 * hd + cy;
        float pw = expf(d2) * wd, ph = expf(d3) * hd;
        float Wf = (float)image_size[1];
        float Hf = (float)image_size[0];
        out[(size_t)m * 4 + 0] = fminf(fmaxf(pcx - 0.5f * pw, 0.f), Wf);
        out[(size_t)m * 4 + 1] = fminf(fmaxf(pcy - 0.5f * ph, 0.f), Hf);
        out[(size_t)m * 4 + 2] = fminf(fmaxf(pcx + 0.5f * pw, 0.f), Wf);
        out[(size_t)m * 4 + 3] = fminf(fmaxf(pcy + 0.5f * ph, 0.f), Hf);
    }
}

// ---------------------------------------------------------------------------
// K4: per-batch stable-descending rank sort. grid = 8, block = 256.
// ---------------------------------------------------------------------------
__global__ __launch_bounds__(256) void k_sort(
    const float* __restrict__ out, float* __restrict__ ws)
{
    __shared__ float ssc[512];
    int t = threadIdx.x, b = blockIdx.x;
    const float* sc_g = out + OUT_SCORES + (size_t)b * 512;
    ssc[t] = sc_g[t];
    ssc[t + 256] = sc_g[t + 256];
    __syncthreads();

#pragma unroll
    for (int ii = 0; ii < 2; ++ii) {
        int i = t + ii * 256;
        float si = ssc[i];
        int r = 0;
        for (int j = 0; j < 512; ++j) {
            float sj = ssc[j];
            r += (int)((sj > si) || (sj == si && j < i));
        }
        f4 v = *(const f4*)(out + ((size_t)b * 512 + i) * 4);
        *(f4*)&ws[WS_SBOX + ((size_t)b * 512 + r) * 4] = v;
        ws[WS_SAREA + (size_t)b * 512 + r] =
            fmaxf(v[2] - v[0], 0.f) * fmaxf(v[3] - v[1], 0.f);
        ((int*)ws)[WS_SIDX + (size_t)b * 512 + r] = i;
    }
}

// ---------------------------------------------------------------------------
// K5: IoU bitmask build. grid = 1024, block = 256 (wave per sorted row i).
// ---------------------------------------------------------------------------
__global__ __launch_bounds__(256) void k_mask(float* __restrict__ ws)
{
    int t = threadIdx.x;
    int wv = t >> 6, lane = t & 63;
    int gi = blockIdx.x * 4 + wv;
    int b = gi >> 9, i = gi & 511;

    f4 bi = *(const f4*)&ws[WS_SBOX + ((size_t)b * 512 + i) * 4];
    float ai = ws[WS_SAREA + (size_t)b * 512 + i];
    unsigned long long* mask = (unsigned long long*)(ws + WS_MASK);

#pragma unroll
    for (int w = 0; w < 8; ++w) {
        int j = w * 64 + lane;
        f4 bj = *(const f4*)&ws[WS_SBOX + ((size_t)b * 512 + j) * 4];
        float aj = ws[WS_SAREA + (size_t)b * 512 + j];
        float xx1 = fmaxf(bi[0], bj[0]), yy1 = fmaxf(bi[1], bj[1]);
        float xx2 = fminf(bi[2], bj[2]), yy2 = fminf(bi[3], bj[3]);
        float inter = fmaxf(xx2 - xx1, 0.f) * fmaxf(yy2 - yy1, 0.f);
        float iou = inter / fmaxf(ai + aj - inter, 1e-9f);
        bool sup = (iou > 0.5f) && (j > i);
        unsigned long long bal = __ballot(sup);
        if (lane == 0) mask[((size_t)b * 512 + i) * 8 + w] = bal;
    }
}

// ---------------------------------------------------------------------------
// K6: sequential greedy pass over bitmasks. grid = 8, block = 64 (1 wave).
// ---------------------------------------------------------------------------
__global__ __launch_bounds__(64) void k_final(
    float* __restrict__ out, const float* __restrict__ wsf)
{
    int lane = threadIdx.x, b = blockIdx.x;
    const unsigned long long* mask =
        (const unsigned long long*)(wsf + WS_MASK) + (size_t)b * 512 * 8;

    unsigned long long kw = ~0ull;
    unsigned long long nxt = (lane < 8) ? mask[lane] : 0ull;

    for (int i = 0; i < 512; ++i) {
        unsigned long long cur = nxt;
        if (i < 511 && lane < 8) nxt = mask[(size_t)(i + 1) * 8 + lane];
        unsigned long long wi = __shfl(kw, i >> 6, 64);
        if ((wi >> (i & 63)) & 1ull) {
            if (lane < 8) kw &= ~cur;
        }
    }

    const int* sidx = ((const int*)wsf) + WS_SIDX + (size_t)b * 512;
#pragma unroll
    for (int w = 0; w < 8; ++w) {
        unsigned long long word = __shfl(kw, w, 64);
        int r = w * 64 + lane;
        out[OUT_KEEP + (size_t)b * 512 + sidx[r]] =
            ((word >> lane) & 1ull) ? 1.0f : 0.0f;
    }
}

// ---------------------------------------------------------------------------
extern "C" void kernel_launch(void* const* d_in, const int* in_sizes, int n_in,
                              void* d_out, int out_size, void* d_ws, size_t ws_size,
                              hipStream_t stream) {
    const float* bfq       = (const float*)d_in[0];
    const float* bfs       = (const float*)d_in[1];
    const float* proposals = (const float*)d_in[2];
    const int*   image_sz  = (const int*)d_in[3];
    const float* W1        = (const float*)d_in[4];
    const float* W2        = (const float*)d_in[5];
    const float* W3        = (const float*)d_in[6];
    const float* Wcor      = (const float*)d_in[7];
    const float* fc1_w     = (const float*)d_in[8];
    const float* fc1_b     = (const float*)d_in[9];
    const float* fc2_w     = (const float*)d_in[10];
    const float* fc2_b     = (const float*)d_in[11];
    const float* sfc_w     = (const float*)d_in[12];
    const float* sfc_b     = (const float*)d_in[13];
    const float* scor_w    = (const float*)d_in[14];
    const float* scor_b    = (const float*)d_in[15];
    const float* spr_w     = (const float*)d_in[16];
    const float* spr_b     = (const float*)d_in[17];
    const float* dpr_w     = (const float*)d_in[18];
    const float* dpr_b     = (const float*)d_in[19];
    float* out = (float*)d_out;
    float* ws  = (float*)d_ws;

    k_prep<<<104, 256, 0, stream>>>(bfs, Wcor, W1, ws);
    k_heavy<<<NM, 256, 0, stream>>>(bfq, W2, W3,
                                    scor_w, scor_b, spr_w, spr_b,
                                    dpr_w, dpr_b,
                                    fc1_w, fc1_b, fc2_w, fc2_b, sfc_w, sfc_b,
                                    proposals, image_sz, ws, out);
    k_sort<<<NB, 256, 0, stream>>>(out, ws);
    k_mask<<<1024, 256, 0, stream>>>(ws);
    k_final<<<NB, 64, 0, stream>>>(out, ws);
}

// Round 15
// 494.624 us; speedup vs baseline: 2.3262x; 2.3262x over previous
//
#include <hip/hip_runtime.h>
#include <math.h>

typedef float f4 __attribute__((ext_vector_type(4)));
typedef f4 f4u __attribute__((aligned(4)));   // 4B-aligned vector load
typedef float f32x4 __attribute__((ext_vector_type(4)));
typedef short short8 __attribute__((ext_vector_type(8)));

constexpr int NB  = 8;
constexpr int NN  = 512;
constexpr int NC  = 256;
constexpr int NHW = 49;
constexpr int NM  = NB * NN;   // 4096
constexpr int XS  = 260;       // k_prep transposed x row stride (floats)

// ---- workspace layout (float offsets) ----
constexpr size_t WS_SMEAN = 0;                        // 8*256              -> 2048
constexpr size_t WS_YST   = 2048;                     // 8*256*49           -> 102400
constexpr size_t WS_UST   = 102400;                   // 8*64*49            -> 127488
constexpr size_t WS_WFH   = 127488;                   // 20*8*64*8 bf16     -> 168448
constexpr size_t WS_WFL   = 168448;                   // same (lo part)     -> 209408
constexpr size_t WS_SP    = 209408;                   // 4096               -> 213504
constexpr size_t WS_QMEAN = 213504;                   // 4096*256           -> 1262080
// NMS region aliases QMEAN (strictly after k_fc consumes it)
constexpr size_t WS_SBOX  = WS_QMEAN;                 // 8*512*4
constexpr size_t WS_SAREA = WS_SBOX + 16384;          // 4096
constexpr size_t WS_SIDX  = WS_SAREA + 4096;          // 4096 (ints)
constexpr size_t WS_MASK  = WS_SIDX + 4096;           // 8*512 u64x8 = 65536 floats

// ---- output layout (floats): boxes[4096*4] | scores[4096] | keep[4096] ----
constexpr size_t OUT_SCORES = (size_t)NM * 4;
constexpr size_t OUT_KEEP   = OUT_SCORES + NM;

__device__ __forceinline__ unsigned short bf16_rne(float f) {
    unsigned u = __float_as_uint(f);
    return (unsigned short)((u + 0x7FFFu + ((u >> 16) & 1u)) >> 16);
}
__device__ __forceinline__ float bf16_to_f(unsigned short h) {
    return __uint_as_float(((unsigned)h) << 16);
}

// stage x [256][49] (global) -> LDS transposed [49][XS] f32 (k_prep only)
__device__ __forceinline__ void stage_xT(const float* __restrict__ g, float* sx, int t) {
#pragma unroll
    for (int rep = 0; rep < 13; ++rep) {
        int id = rep * 256 + t;
        if (id < 3136) {
            int c4 = id / 49;
            int hw = id - c4 * 49;
            f4 v;
            v[0] = g[(c4 * 4 + 0) * 49 + hw];
            v[1] = g[(c4 * 4 + 1) * 49 + hw];
            v[2] = g[(c4 * 4 + 2) * 49 + hw];
            v[3] = g[(c4 * 4 + 3) * 49 + hw];
            *(f4*)&sx[hw * XS + c4 * 4] = v;
        }
    }
}

// ---------------------------------------------------------------------------
// K1: merged prep. grid = 104, block = 256.
//  blocks 0..63  : per-batch precompute (b = blk>>3, og8 = blk&7: 32 y_s rows
//                  each; og8<2 also 32 u_s rows; og8==0 also smean).
//  blocks 64..103: split-bf16 A-fragment build (4 old 64-lane blocks each).
// ---------------------------------------------------------------------------
__global__ __launch_bounds__(256, 2) void k_prep(
    const float* __restrict__ bfs, const float* __restrict__ Wcor,
    const float* __restrict__ W1, float* __restrict__ ws)
{
    int t = threadIdx.x, blk = blockIdx.x;

    if (blk >= 64) {
        // ---- A-fragment build: old k_wfrag blocks (blk-64)*4 + (t>>6) ----
        int ob = (blk - 64) * 4 + (t >> 6);    // 0..159
        int l = t & 63;
        int mt = ob >> 3, ks = ob & 7;
        int row = mt * 16 + (l & 15);
        int k0 = ks * 32 + (l >> 4) * 8;
        const float* src = (row < 256) ? (Wcor + (size_t)row * 256 + k0)
                                       : (W1 + (size_t)(row - 256) * 512 + k0);
        short hv[8], lv[8];
#pragma unroll
        for (int j = 0; j < 8; ++j) {
            float v = src[j];
            unsigned short hh = bf16_rne(v);
            unsigned short hl = bf16_rne(v - bf16_to_f(hh));
            hv[j] = (short)hh; lv[j] = (short)hl;
        }
        short* dh = (short*)(ws + WS_WFH) + ((size_t)ob * 64 + l) * 8;
        short* dl = (short*)(ws + WS_WFL) + ((size_t)ob * 64 + l) * 8;
#pragma unroll
        for (int j = 0; j < 8; ++j) { dh[j] = hv[j]; dl[j] = lv[j]; }
        return;
    }

    __shared__ __align__(16) float smem[49 * XS + 16];
    float* sx = smem;
    int b = blk >> 3;
    int og8 = blk & 7;

    stage_xT(bfs + (size_t)b * 12544, sx, t);
    __syncthreads();

    if (og8 == 0) {
        float s = 0.f;
        for (int hw = 0; hw < 49; ++hw) s += sx[hw * XS + t];
        ws[WS_SMEAN + (size_t)b * 256 + t] = s * (1.f / 49.f);
    }

    int og2 = t >> 3, hwg = t & 7;       // og2: 0..31, one y_s row each
    int hwb = (hwg == 7) ? 0 : hwg * 7;
    int oA = og8 * 32 + og2;
    bool do_u = (og8 < 2);
    int o2 = og8 * 32 + og2;             // u_s row (valid when do_u)

    float acc0[7] = {0,0,0,0,0,0,0};
    float a1a[7]  = {0,0,0,0,0,0,0};
    const float* xrow = sx + hwb * XS;
    const float* w0r = Wcor + (size_t)oA * 256;
    const float* war = W1 + (size_t)o2 * 512 + 256;   // s-part

#pragma unroll 1
    for (int c4 = 0; c4 < 64; ++c4) {
        f4 xv[7];
#pragma unroll
        for (int i = 0; i < 7; ++i) xv[i] = *(const f4*)&xrow[i * XS + c4 * 4];
        f4 w0 = *(const f4*)&w0r[c4 * 4];
        f4 wa = *(const f4*)&war[c4 * 4];
#pragma unroll
        for (int j = 0; j < 4; ++j) {
#pragma unroll
            for (int i = 0; i < 7; ++i) {
                float x = xv[i][j];
                acc0[i] = fmaf(w0[j], x, acc0[i]);
                a1a[i]  = fmaf(wa[j], x, a1a[i]);
            }
        }
    }

    if (hwg < 7) {
#pragma unroll
        for (int i = 0; i < 7; ++i) {
            int hw = hwb + i;
            ws[WS_YST + ((size_t)b * 256 + oA) * 49 + hw] = acc0[i];
            if (do_u)
                ws[WS_UST + ((size_t)b * 64 + o2) * 49 + hw] = a1a[i];
        }
    }
}

// ---------------------------------------------------------------------------
// K2: heavy per-m kernel (round-13 version — verified ~370 us, no spill).
// MFMA fused K-loop; both x_hi/x_lo in LDS; broadcast-conv phase 2.
// FC path stays SEPARATE (round-14 lesson: fusing kills the 8-16x weight
// amortization of k_fc and spills q_sum).
// ---------------------------------------------------------------------------
__global__ __launch_bounds__(256, 3) void k_heavy(
    const float* __restrict__ bfq,
    const float* __restrict__ W2, const float* __restrict__ W3,
    const float* __restrict__ scor_w, const float* __restrict__ scor_b,
    const float* __restrict__ spr_w, const float* __restrict__ spr_b,
    const float* __restrict__ dpr_w, const float* __restrict__ dpr_b,
    const float* __restrict__ proposals, const int* __restrict__ image_size,
    float* __restrict__ ws, float* __restrict__ out)
{
    __shared__ __align__(16) short xh[49 * 256];   // 24.5 KiB
    __shared__ __align__(16) short xl[49 * 256];   // 24.5 KiB
    __shared__ float red[20];

    int t = threadIdx.x, m = blockIdx.x, b = m >> 9;
    const float* xg = bfq + (size_t)m * 12544 + (size_t)t * 49;

    // ---- stage x -> bf16 hi AND lo (all 13 loads issued unrolled) ----
    {
        float qs = 0.f;
#pragma unroll
        for (int r = 0; r < 12; ++r) {
            f4u v = *(const f4u*)&xg[r * 4];
#pragma unroll
            for (int j = 0; j < 4; ++j) {
                int hw = r * 4 + j;
                float x = v[j];
                qs += x;
                unsigned short hh = bf16_rne(x);
                int idx = (hw * 256 + t) ^ ((hw & 7) << 3);
                xh[idx] = (short)hh;
                xl[idx] = (short)bf16_rne(x - bf16_to_f(hh));
            }
        }
        float x48 = xg[48];
        qs += x48;
        unsigned short hh48 = bf16_rne(x48);
        xh[48 * 256 + t] = (short)hh48;            // 48&7 == 0 -> no xor
        xl[48 * 256 + t] = (short)bf16_rne(x48 - bf16_to_f(hh48));
        ws[WS_QMEAN + (size_t)m * 256 + t] = qs * (1.f / 49.f);
    }
    __syncthreads();

    int w = t >> 6, l = t & 63, cl = l & 15, g = l >> 4;

    f32x4 acc[5][4];
#pragma unroll
    for (int i = 0; i < 5; ++i)
#pragma unroll
        for (int nt = 0; nt < 4; ++nt) acc[i][nt] = (f32x4)0.f;

    const short* wfH = (const short*)(ws + WS_WFH);
    const short* wfL = (const short*)(ws + WS_WFL);

    // precompute the 4 clamped B-column base offsets (col>=49 -> col 0)
    int bcol[4];
#pragma unroll
    for (int nt = 0; nt < 4; ++nt) {
        int col = nt * 16 + cl;
        if (col >= 49) col = 0;
        bcol[nt] = col;
    }

    // ---- fused K-loop: acc += Wh*xh + Wh*xl + Wl*xh ----
#pragma unroll 1
    for (int ks = 0; ks < 8; ++ks) {
        short8 bh[4], bl[4];
#pragma unroll
        for (int nt = 0; nt < 4; ++nt) {
            int col = bcol[nt];
            int idx = (col * 256 + ks * 32 + g * 8) ^ ((col & 7) << 3);
            bh[nt] = *(const short8*)&xh[idx];
            bl[nt] = *(const short8*)&xl[idx];
        }
#pragma unroll
        for (int i = 0; i < 5; ++i) {
            int mt = w + 4 * i;
            size_t off = ((size_t)(mt * 8 + ks) * 64 + l) * 8;
            short8 ah = *(const short8*)&wfH[off];
            short8 al = *(const short8*)&wfL[off];
            acc[i][0] = __builtin_amdgcn_mfma_f32_16x16x32_bf16(ah, bh[0], acc[i][0], 0, 0, 0);
            acc[i][1] = __builtin_amdgcn_mfma_f32_16x16x32_bf16(ah, bh[1], acc[i][1], 0, 0, 0);
            acc[i][2] = __builtin_amdgcn_mfma_f32_16x16x32_bf16(ah, bh[2], acc[i][2], 0, 0, 0);
            acc[i][3] = __builtin_amdgcn_mfma_f32_16x16x32_bf16(ah, bh[3], acc[i][3], 0, 0, 0);
            acc[i][0] = __builtin_amdgcn_mfma_f32_16x16x32_bf16(ah, bl[0], acc[i][0], 0, 0, 0);
            acc[i][1] = __builtin_amdgcn_mfma_f32_16x16x32_bf16(ah, bl[1], acc[i][1], 0, 0, 0);
            acc[i][2] = __builtin_amdgcn_mfma_f32_16x16x32_bf16(ah, bl[2], acc[i][2], 0, 0, 0);
            acc[i][3] = __builtin_amdgcn_mfma_f32_16x16x32_bf16(ah, bl[3], acc[i][3], 0, 0, 0);
            acc[i][0] = __builtin_amdgcn_mfma_f32_16x16x32_bf16(al, bh[0], acc[i][0], 0, 0, 0);
            acc[i][1] = __builtin_amdgcn_mfma_f32_16x16x32_bf16(al, bh[1], acc[i][1], 0, 0, 0);
            acc[i][2] = __builtin_amdgcn_mfma_f32_16x16x32_bf16(al, bh[2], acc[i][2], 0, 0, 0);
            acc[i][3] = __builtin_amdgcn_mfma_f32_16x16x32_bf16(al, bh[3], acc[i][3], 0, 0, 0);
        }
    }

    // ---- corr epilogue: tiles w,w+4,w+8,w+12 = Wcor rows (<256).
    // C/D layout (m89): col = lane&15, row_in_tile = (lane>>4)*4 + reg.
    float csum = 0.f;
    {
        const float* yb = ws + WS_YST + (size_t)b * 256 * 49;
#pragma unroll
        for (int i = 0; i < 4; ++i) {
            int row0 = (w + 4 * i) * 16 + g * 4;
#pragma unroll
            for (int q = 0; q < 4; ++q) {
                int row = row0 + q;
                float p = 0.f;
#pragma unroll
                for (int nt = 0; nt < 4; ++nt) {
                    int col = nt * 16 + cl;
                    if (col < 49) p += acc[i][nt][q] * yb[(size_t)row * 49 + col];
                }
                p += __shfl_xor(p, 1, 64);
                p += __shfl_xor(p, 2, 64);
                p += __shfl_xor(p, 4, 64);
                p += __shfl_xor(p, 8, 64);
                if (cl == 0) csum += fmaxf(p, 0.f) * scor_w[row];
            }
        }
    }
    __syncthreads();   // ALL waves done with MFMA B-reads; xh/xl reusable

    // ---- x1 epilogue: tile w+16 = W1q rows; write s1[64][52] over xh ----
    float* s1    = (float*)xh;                 // [64][52]   3328 floats
    float* sp1   = s1 + 64 * 52;               // [64][28]   1792 -> 5120 <= 6272
    float* cpart = (float*)xl;                 // [4][64][11] 2816 floats
    float* sc2T  = cpart + 2816;               // [9][64]     576 -> 3392 <= 6272
    {
        const float* ub = ws + WS_UST + (size_t)b * 64 * 49;
        int ch0 = w * 16 + g * 4;
#pragma unroll
        for (int q = 0; q < 4; ++q) {
            int ch = ch0 + q;
#pragma unroll
            for (int nt = 0; nt < 4; ++nt) {
                int col = nt * 16 + cl;
                if (col < 49)
                    s1[ch * 52 + col] = fmaxf(acc[4][nt][q] + ub[(size_t)ch * 49 + col], 0.f);
            }
        }
    }
    __syncthreads();

    // ---- avgpool3 7x7 -> 5x5, padded [64][28] ----
    for (int i = t; i < 64 * 25; i += 256) {
        int ch = i / 25, pos = i - ch * 25;
        int py = pos / 5, px = pos - py * 5;
        const float* base = s1 + ch * 52 + py * 7 + px;
        float s = base[0] + base[1] + base[2]
                + base[7] + base[8] + base[9]
                + base[14] + base[15] + base[16];
        sp1[ch * 28 + pos] = s * (1.f / 9.f);
    }
    __syncthreads();

    // ---- conv3x3 VALID 64->64, thread = (oc, icq=wave) ----
    {
        int oc = t & 63, icq = t >> 6;
        float a9[9] = {0,0,0,0,0,0,0,0,0};
        const float* wb2 = W2 + (size_t)oc * 576 + icq * 16 * 9;
#pragma unroll 1
        for (int ic16 = 0; ic16 < 16; ++ic16) {
            int ic = icq * 16 + ic16;
            const f4* ar = (const f4*)(sp1 + ic * 28);
            float av[28];
            *(f4*)&av[0]  = ar[0];
            *(f4*)&av[4]  = ar[1];
            *(f4*)&av[8]  = ar[2];
            *(f4*)&av[12] = ar[3];
            *(f4*)&av[16] = ar[4];
            *(f4*)&av[20] = ar[5];
            *(f4*)&av[24] = ar[6];
            const float* wi = wb2 + ic16 * 9;
            f4u w0 = *(const f4u*)wi;
            f4u w1 = *(const f4u*)(wi + 4);
            float wv[9] = { w0[0], w0[1], w0[2], w0[3], w1[0], w1[1], w1[2], w1[3], wi[8] };
#pragma unroll
            for (int py = 0; py < 3; ++py)
#pragma unroll
                for (int px = 0; px < 3; ++px) {
                    int p9 = py * 3 + px;
#pragma unroll
                    for (int ky = 0; ky < 3; ++ky)
#pragma unroll
                        for (int kx = 0; kx < 3; ++kx)
                            a9[p9] = fmaf(wv[ky * 3 + kx],
                                          av[(py + ky) * 5 + (px + kx)], a9[p9]);
                }
        }
#pragma unroll
        for (int p = 0; p < 9; ++p)
            cpart[((size_t)icq * 64 + oc) * 11 + p] = a9[p];
    }
    __syncthreads();

    // combine 4 partials + relu -> sc2T[pos][oc]
    for (int i = t; i < 576; i += 256) {
        int pos = i >> 6, occ = i & 63;
        float s = cpart[((size_t)0 * 64 + occ) * 11 + pos]
                + cpart[((size_t)1 * 64 + occ) * 11 + pos]
                + cpart[((size_t)2 * 64 + occ) * 11 + pos]
                + cpart[((size_t)3 * 64 + occ) * 11 + pos];
        sc2T[pos * 64 + occ] = fmaxf(s, 0.f);
    }
    __syncthreads();

    // ---- W3 (256x64) + relu + avgpool3 3x3 -> 1 (broadcast f4 reads) ----
    float xfin;
    {
        float xw[9] = {0,0,0,0,0,0,0,0,0};
        const f4* wr = (const f4*)(W3 + (size_t)t * 64);
#pragma unroll 1
        for (int gg = 0; gg < 16; ++gg) {
            f4 wv4 = wr[gg];
#pragma unroll
            for (int p = 0; p < 9; ++p) {
                f4 c = *(const f4*)(sc2T + p * 64 + gg * 4);
                xw[p] = fmaf(wv4[0], c[0], xw[p]);
                xw[p] = fmaf(wv4[1], c[1], xw[p]);
                xw[p] = fmaf(wv4[2], c[2], xw[p]);
                xw[p] = fmaf(wv4[3], c[3], xw[p]);
            }
        }
        float s = 0.f;
#pragma unroll
        for (int p = 0; p < 9; ++p) s += fmaxf(xw[p], 0.f);
        xfin = s * (1.f / 9.f);
    }

    // ---- merged 5-way block reduction: ONE barrier ----
    float v0 = xfin * spr_w[t] + csum;
    float v1 = xfin * dpr_w[0 * 256 + t];
    float v2 = xfin * dpr_w[1 * 256 + t];
    float v3 = xfin * dpr_w[2 * 256 + t];
    float v4 = xfin * dpr_w[3 * 256 + t];
#pragma unroll
    for (int off = 32; off > 0; off >>= 1) {
        v0 += __shfl_xor(v0, off, 64);
        v1 += __shfl_xor(v1, off, 64);
        v2 += __shfl_xor(v2, off, 64);
        v3 += __shfl_xor(v3, off, 64);
        v4 += __shfl_xor(v4, off, 64);
    }
    if (l == 0) {
        red[w * 5 + 0] = v0; red[w * 5 + 1] = v1; red[w * 5 + 2] = v2;
        red[w * 5 + 3] = v3; red[w * 5 + 4] = v4;
    }
    __syncthreads();

    if (t == 0) {
        float r_s  = red[0] + red[5] + red[10] + red[15];
        float r_d0 = red[1] + red[6] + red[11] + red[16];
        float r_d1 = red[2] + red[7] + red[12] + red[17];
        float r_d2 = red[3] + red[8] + red[13] + red[18];
        float r_d3 = red[4] + red[9] + red[14] + red[19];

        ws[WS_SP + m] = r_s + spr_b[0] + scor_b[0];

        float d0 = r_d0 + dpr_b[0];
        float d1 = r_d1 + dpr_b[1];
        float d2 = fminf(r_d2 + dpr_b[2], 4.135166556742356f);
        float d3 = fminf(r_d3 + dpr_b[3], 4.135166556742356f);

        const float* pr = proposals + (size_t)m * 4;
        float x1p = pr[0], y1p = pr[1], x2p = pr[2], y2p = pr[3];
        float wd = x2p - x1p, hd = y2p - y1p;
        float cx = x1p + 0.5f * wd, cy = y1p + 0.5f * hd;
        float pcx = d0 * wd + cx, pcy = d1 * hd + cy;
        float pw = expf(d2) * wd, ph = expf(d3) * hd;
        float Wf = (float)image_size[1];
        float Hf = (float)image_size[0];
        out[(size_t)m * 4 + 0] = fminf(fmaxf(pcx - 0.5f * pw, 0.f), Wf);
        out[(size_t)m * 4 + 1] = fminf(fmaxf(pcy - 0.5f * ph, 0.f), Hf);
        out[(size_t)m * 4 + 2] = fminf(fmaxf(pcx + 0.5f * pw, 0.f), Wf);
        out[(size_t)m * 4 + 3] = fminf(fmaxf(pcy + 0.5f * ph, 0.f), Hf);
    }
}

// ---------------------------------------------------------------------------
// K3: FC path, 16 m's per block (double weight amortization vs round 13).
// grid = 256, block = 256. One-barrier merged final reduction.
// ---------------------------------------------------------------------------
__global__ __launch_bounds__(256) void k_fc(
    const float* __restrict__ fc1_w, const float* __restrict__ fc1_b,
    const float* __restrict__ fc2_w, const float* __restrict__ fc2_b,
    const float* __restrict__ sfc_w, const float* __restrict__ sfc_b,
    float* __restrict__ ws, float* __restrict__ out)
{
    __shared__ __align__(16) float sxfc[16][512];   // 32 KB
    __shared__ __align__(16) float sh1[16][256];    // 16 KB
    __shared__ float s_red[64];
    int t = threadIdx.x;
    int m0 = blockIdx.x * 16;
    int w = t >> 6, l = t & 63;

#pragma unroll
    for (int mi = 0; mi < 16; ++mi) {
        int mg = m0 + mi;
        int b = mg >> 9;
        sxfc[mi][t]       = ws[WS_QMEAN + (size_t)mg * 256 + t];
        sxfc[mi][256 + t] = ws[WS_SMEAN + (size_t)b * 256 + t];
    }
    __syncthreads();

    {
        const f4* wr = (const f4*)(fc1_w + t * 512);
        float acc[16];
#pragma unroll
        for (int mi = 0; mi < 16; ++mi) acc[mi] = 0.f;
#pragma unroll 1
        for (int k4 = 0; k4 < 128; ++k4) {
            f4 wv = wr[k4];
#pragma unroll
            for (int mi = 0; mi < 16; ++mi) {
                f4 x = ((const f4*)sxfc[mi])[k4];
                acc[mi] = fmaf(wv[0], x[0], acc[mi]);
                acc[mi] = fmaf(wv[1], x[1], acc[mi]);
                acc[mi] = fmaf(wv[2], x[2], acc[mi]);
                acc[mi] = fmaf(wv[3], x[3], acc[mi]);
            }
        }
        float bb = fc1_b[t];
#pragma unroll
        for (int mi = 0; mi < 16; ++mi) sh1[mi][t] = fmaxf(acc[mi] + bb, 0.f);
    }
    __syncthreads();

    float val[16];
    {
        const f4* wr = (const f4*)(fc2_w + t * 256);
        float acc[16];
#pragma unroll
        for (int mi = 0; mi < 16; ++mi) acc[mi] = 0.f;
#pragma unroll 1
        for (int k4 = 0; k4 < 64; ++k4) {
            f4 wv = wr[k4];
#pragma unroll
            for (int mi = 0; mi < 16; ++mi) {
                f4 x = ((const f4*)sh1[mi])[k4];
                acc[mi] = fmaf(wv[0], x[0], acc[mi]);
                acc[mi] = fmaf(wv[1], x[1], acc[mi]);
                acc[mi] = fmaf(wv[2], x[2], acc[mi]);
                acc[mi] = fmaf(wv[3], x[3], acc[mi]);
            }
        }
        float bb = fc2_b[t];
        float sw = sfc_w[t];
#pragma unroll
        for (int mi = 0; mi < 16; ++mi) val[mi] = sw * fmaxf(acc[mi] + bb, 0.f);
    }

    // merged 16-way reduction: one barrier
#pragma unroll
    for (int mi = 0; mi < 16; ++mi) {
        float v = val[mi];
#pragma unroll
        for (int off = 32; off > 0; off >>= 1) v += __shfl_xor(v, off, 64);
        if (l == 0) s_red[w * 16 + mi] = v;
    }
    __syncthreads();

    if (t < 16) {
        float r = s_red[0 * 16 + t] + s_red[1 * 16 + t]
                + s_red[2 * 16 + t] + s_red[3 * 16 + t];
        float tot = ws[WS_SP + m0 + t] + (r + sfc_b[0]);
        out[OUT_SCORES + m0 + t] = 1.0f / (1.0f + expf(-tot));
    }
}

// ---------------------------------------------------------------------------
// K4: per-batch stable-descending rank sort. grid = 8, block = 256.
// ---------------------------------------------------------------------------
__global__ __launch_bounds__(256) void k_sort(
    const float* __restrict__ out, float* __restrict__ ws)
{
    __shared__ float ssc[512];
    int t = threadIdx.x, b = blockIdx.x;
    const float* sc_g = out + OUT_SCORES + (size_t)b * 512;
    ssc[t] = sc_g[t];
    ssc[t + 256] = sc_g[t + 256];
    __syncthreads();

#pragma unroll
    for (int ii = 0; ii < 2; ++ii) {
        int i = t + ii * 256;
        float si = ssc[i];
        int r = 0;
        for (int j = 0; j < 512; ++j) {
            float sj = ssc[j];
            r += (int)((sj > si) || (sj == si && j < i));
        }
        f4 v = *(const f4*)(out + ((size_t)b * 512 + i) * 4);
        *(f4*)&ws[WS_SBOX + ((size_t)b * 512 + r) * 4] = v;
        ws[WS_SAREA + (size_t)b * 512 + r] =
            fmaxf(v[2] - v[0], 0.f) * fmaxf(v[3] - v[1], 0.f);
        ((int*)ws)[WS_SIDX + (size_t)b * 512 + r] = i;
    }
}

// ---------------------------------------------------------------------------
// K5: IoU bitmask build. grid = 1024, block = 256 (wave per sorted row i).
// ---------------------------------------------------------------------------
__global__ __launch_bounds__(256) void k_mask(float* __restrict__ ws)
{
    int t = threadIdx.x;
    int wv = t >> 6, lane = t & 63;
    int gi = blockIdx.x * 4 + wv;
    int b = gi >> 9, i = gi & 511;

    f4 bi = *(const f4*)&ws[WS_SBOX + ((size_t)b * 512 + i) * 4];
    float ai = ws[WS_SAREA + (size_t)b * 512 + i];
    unsigned long long* mask = (unsigned long long*)(ws + WS_MASK);

#pragma unroll
    for (int w = 0; w < 8; ++w) {
        int j = w * 64 + lane;
        f4 bj = *(const f4*)&ws[WS_SBOX + ((size_t)b * 512 + j) * 4];
        float aj = ws[WS_SAREA + (size_t)b * 512 + j];
        float xx1 = fmaxf(bi[0], bj[0]), yy1 = fmaxf(bi[1], bj[1]);
        float xx2 = fminf(bi[2], bj[2]), yy2 = fminf(bi[3], bj[3]);
        float inter = fmaxf(xx2 - xx1, 0.f) * fmaxf(yy2 - yy1, 0.f);
        float iou = inter / fmaxf(ai + aj - inter, 1e-9f);
        bool sup = (iou > 0.5f) && (j > i);
        unsigned long long bal = __ballot(sup);
        if (lane == 0) mask[((size_t)b * 512 + i) * 8 + w] = bal;
    }
}

// ---------------------------------------------------------------------------
// K6: sequential greedy pass over bitmasks. grid = 8, block = 64 (1 wave).
// ---------------------------------------------------------------------------
__global__ __launch_bounds__(64) void k_final(
    float* __restrict__ out, const float* __restrict__ wsf)
{
    int lane = threadIdx.x, b = blockIdx.x;
    const unsigned long long* mask =
        (const unsigned long long*)(wsf + WS_MASK) + (size_t)b * 512 * 8;

    unsigned long long kw = ~0ull;
    unsigned long long nxt = (lane < 8) ? mask[lane] : 0ull;

    for (int i = 0; i < 512; ++i) {
        unsigned long long cur = nxt;
        if (i < 511 && lane < 8) nxt = mask[(size_t)(i + 1) * 8 + lane];
        unsigned long long wi = __shfl(kw, i >> 6, 64);
        if ((wi >> (i & 63)) & 1ull) {
            if (lane < 8) kw &= ~cur;
        }
    }

    const int* sidx = ((const int*)wsf) + WS_SIDX + (size_t)b * 512;
#pragma unroll
    for (int w = 0; w < 8; ++w) {
        unsigned long long word = __shfl(kw, w, 64);
        int r = w * 64 + lane;
        out[OUT_KEEP + (size_t)b * 512 + sidx[r]] =
            ((word >> lane) & 1ull) ? 1.0f : 0.0f;
    }
}

// ---------------------------------------------------------------------------
extern "C" void kernel_launch(void* const* d_in, const int* in_sizes, int n_in,
                              void* d_out, int out_size, void* d_ws, size_t ws_size,
                              hipStream_t stream) {
    const float* bfq       = (const float*)d_in[0];
    const float* bfs       = (const float*)d_in[1];
    const float* proposals = (const float*)d_in[2];
    const int*   image_sz  = (const int*)d_in[3];
    const float* W1        = (const float*)d_in[4];
    const float* W2        = (const float*)d_in[5];
    const float* W3        = (const float*)d_in[6];
    const float* Wcor      = (const float*)d_in[7];
    const float* fc1_w     = (const float*)d_in[8];
    const float* fc1_b     = (const float*)d_in[9];
    const float* fc2_w     = (const float*)d_in[10];
    const float* fc2_b     = (const float*)d_in[11];
    const float* sfc_w     = (const float*)d_in[12];
    const float* sfc_b     = (const float*)d_in[13];
    const float* scor_w    = (const float*)d_in[14];
    const float* scor_b    = (const float*)d_in[15];
    const float* spr_w     = (const float*)d_in[16];
    const float* spr_b     = (const float*)d_in[17];
    const float* dpr_w     = (const float*)d_in[18];
    const float* dpr_b     = (const float*)d_in[19];
    float* out = (float*)d_out;
    float* ws  = (float*)d_ws;

    k_prep<<<104, 256, 0, stream>>>(bfs, Wcor, W1, ws);
    k_heavy<<<NM, 256, 0, stream>>>(bfq, W2, W3,
                                    scor_w, scor_b, spr_w, spr_b,
                                    dpr_w, dpr_b, proposals, image_sz, ws, out);
    k_fc<<<NM / 16, 256, 0, stream>>>(fc1_w, fc1_b, fc2_w, fc2_b,
                                      sfc_w, sfc_b, ws, out);
    k_sort<<<NB, 256, 0, stream>>>(out, ws);
    k_mask<<<1024, 256, 0, stream>>>(ws);
    k_final<<<NB, 64, 0, stream>>>(out, ws);
}

// Round 16
// 448.142 us; speedup vs baseline: 2.5675x; 1.1037x over previous
//
#include <hip/hip_runtime.h>
#include <math.h>

typedef float f4 __attribute__((ext_vector_type(4)));
typedef f4 f4u __attribute__((aligned(4)));   // 4B-aligned vector load
typedef float f32x4 __attribute__((ext_vector_type(4)));
typedef short short8 __attribute__((ext_vector_type(8)));

constexpr int NB  = 8;
constexpr int NN  = 512;
constexpr int NC  = 256;
constexpr int NHW = 49;
constexpr int NM  = NB * NN;   // 4096
constexpr int XS  = 260;       // k_prep transposed x row stride (floats)

// ---- workspace layout (float offsets) ----
constexpr size_t WS_SMEAN = 0;                        // 8*256              -> 2048
constexpr size_t WS_YST   = 2048;                     // 8*256*49           -> 102400
constexpr size_t WS_UST   = 102400;                   // 8*64*49            -> 127488
constexpr size_t WS_WFH   = 127488;                   // 20*8*64*8 bf16     -> 168448
constexpr size_t WS_WFL   = 168448;                   // same (lo part)     -> 209408
constexpr size_t WS_SP    = 209408;                   // 4096               -> 213504
constexpr size_t WS_QMEAN = 213504;                   // 4096*256           -> 1262080
// W2 MFMA fragments (only used when ws_size is big enough):
constexpr size_t WS_W2FH  = 1262080;                  // 4*18*64*8 bf16 = 18432 f
constexpr size_t WS_W2FL  = 1280512;                  // -> end 1298944 floats
constexpr size_t WS_NEED_BIG = 1298944;

// ---- output layout (floats): boxes[4096*4] | scores[4096] | keep[4096] ----
constexpr size_t OUT_SCORES = (size_t)NM * 4;
constexpr size_t OUT_KEEP   = OUT_SCORES + NM;

__device__ __forceinline__ float block_reduce_sum(float v, float* red) {
    int t = threadIdx.x;
#pragma unroll
    for (int off = 32; off > 0; off >>= 1) v += __shfl_down(v, off, 64);
    __syncthreads();
    if ((t & 63) == 0) red[t >> 6] = v;
    __syncthreads();
    return red[0] + red[1] + red[2] + red[3];
}

__device__ __forceinline__ unsigned short bf16_rne(float f) {
    unsigned u = __float_as_uint(f);
    return (unsigned short)((u + 0x7FFFu + ((u >> 16) & 1u)) >> 16);
}
__device__ __forceinline__ float bf16_to_f(unsigned short h) {
    return __uint_as_float(((unsigned)h) << 16);
}

// stage x [256][49] (global) -> LDS transposed [49][XS] f32 (k_prep only)
__device__ __forceinline__ void stage_xT(const float* __restrict__ g, float* sx, int t) {
#pragma unroll
    for (int rep = 0; rep < 13; ++rep) {
        int id = rep * 256 + t;
        if (id < 3136) {
            int c4 = id / 49;
            int hw = id - c4 * 49;
            f4 v;
            v[0] = g[(c4 * 4 + 0) * 49 + hw];
            v[1] = g[(c4 * 4 + 1) * 49 + hw];
            v[2] = g[(c4 * 4 + 2) * 49 + hw];
            v[3] = g[(c4 * 4 + 3) * 49 + hw];
            *(f4*)&sx[hw * XS + c4 * 4] = v;
        }
    }
}

// ---------------------------------------------------------------------------
// K1: merged prep. grid = 104 (+18 when big ws), block = 256.
//  blocks 0..63   : per-batch precompute (y_s / u_s / smean)
//  blocks 64..103 : split-bf16 A-fragments for [Wcor;W1q]
//  blocks 104..121: split-bf16 A-fragments for W2 (64x576), ks = blk-104
// ---------------------------------------------------------------------------
__global__ __launch_bounds__(256, 2) void k_prep(
    const float* __restrict__ bfs, const float* __restrict__ Wcor,
    const float* __restrict__ W1, const float* __restrict__ W2,
    float* __restrict__ ws, int use_mfma_conv)
{
    int t = threadIdx.x, blk = blockIdx.x;

    if (blk >= 104) {                     // W2 fragment build (big-ws only)
        if (!use_mfma_conv) return;
        int ks2 = blk - 104;              // 0..17
        int mt = t >> 6, l = t & 63;
        int row = mt * 16 + (l & 15);
        int kk0 = ks2 * 32 + (l >> 4) * 8;
        const float* src = W2 + (size_t)row * 576 + kk0;
        short* dh = (short*)(ws + WS_W2FH) + ((size_t)(mt * 18 + ks2) * 64 + l) * 8;
        short* dl = (short*)(ws + WS_W2FL) + ((size_t)(mt * 18 + ks2) * 64 + l) * 8;
#pragma unroll
        for (int j = 0; j < 8; ++j) {
            float v = src[j];
            unsigned short hh = bf16_rne(v);
            dh[j] = (short)hh;
            dl[j] = (short)bf16_rne(v - bf16_to_f(hh));
        }
        return;
    }

    if (blk >= 64) {
        // ---- [Wcor;W1q] A-fragment build ----
        int ob = (blk - 64) * 4 + (t >> 6);    // 0..159
        int l = t & 63;
        int mt = ob >> 3, ks = ob & 7;
        int row = mt * 16 + (l & 15);
        int k0 = ks * 32 + (l >> 4) * 8;
        const float* src = (row < 256) ? (Wcor + (size_t)row * 256 + k0)
                                       : (W1 + (size_t)(row - 256) * 512 + k0);
        short hv[8], lv[8];
#pragma unroll
        for (int j = 0; j < 8; ++j) {
            float v = src[j];
            unsigned short hh = bf16_rne(v);
            unsigned short hl = bf16_rne(v - bf16_to_f(hh));
            hv[j] = (short)hh; lv[j] = (short)hl;
        }
        short* dh = (short*)(ws + WS_WFH) + ((size_t)ob * 64 + l) * 8;
        short* dl = (short*)(ws + WS_WFL) + ((size_t)ob * 64 + l) * 8;
#pragma unroll
        for (int j = 0; j < 8; ++j) { dh[j] = hv[j]; dl[j] = lv[j]; }
        return;
    }

    __shared__ __align__(16) float smem[49 * XS + 16];
    float* sx = smem;
    int b = blk >> 3;
    int og8 = blk & 7;

    stage_xT(bfs + (size_t)b * 12544, sx, t);
    __syncthreads();

    if (og8 == 0) {
        float s = 0.f;
        for (int hw = 0; hw < 49; ++hw) s += sx[hw * XS + t];
        ws[WS_SMEAN + (size_t)b * 256 + t] = s * (1.f / 49.f);
    }

    int og2 = t >> 3, hwg = t & 7;
    int hwb = (hwg == 7) ? 0 : hwg * 7;
    int oA = og8 * 32 + og2;
    bool do_u = (og8 < 2);
    int o2 = og8 * 32 + og2;

    float acc0[7] = {0,0,0,0,0,0,0};
    float a1a[7]  = {0,0,0,0,0,0,0};
    const float* xrow = sx + hwb * XS;
    const float* w0r = Wcor + (size_t)oA * 256;
    const float* war = W1 + (size_t)o2 * 512 + 256;

#pragma unroll 1
    for (int c4 = 0; c4 < 64; ++c4) {
        f4 xv[7];
#pragma unroll
        for (int i = 0; i < 7; ++i) xv[i] = *(const f4*)&xrow[i * XS + c4 * 4];
        f4 w0 = *(const f4*)&w0r[c4 * 4];
        f4 wa = *(const f4*)&war[c4 * 4];
#pragma unroll
        for (int j = 0; j < 4; ++j) {
#pragma unroll
            for (int i = 0; i < 7; ++i) {
                float x = xv[i][j];
                acc0[i] = fmaf(w0[j], x, acc0[i]);
                a1a[i]  = fmaf(wa[j], x, a1a[i]);
            }
        }
    }

    if (hwg < 7) {
#pragma unroll
        for (int i = 0; i < 7; ++i) {
            int hw = hwb + i;
            ws[WS_YST + ((size_t)b * 256 + oA) * 49 + hw] = acc0[i];
            if (do_u)
                ws[WS_UST + ((size_t)b * 64 + o2) * 49 + hw] = a1a[i];
        }
    }
}

// ---------------------------------------------------------------------------
// K2: heavy per-m kernel. MFMA fused K-loop; phase-2 conv either as
// split-bf16 MFMA (64x576 @ 576x9 GEMM, big-ws path) or the proven
// broadcast VALU conv (fallback). 3 blocks/CU.
// ---------------------------------------------------------------------------
__global__ __launch_bounds__(256, 3) void k_heavy(
    const float* __restrict__ bfq,
    const float* __restrict__ W2, const float* __restrict__ W3,
    const float* __restrict__ scor_w, const float* __restrict__ scor_b,
    const float* __restrict__ spr_w, const float* __restrict__ spr_b,
    const float* __restrict__ dpr_w, const float* __restrict__ dpr_b,
    const float* __restrict__ proposals, const int* __restrict__ image_size,
    float* __restrict__ ws, float* __restrict__ out, int use_mfma_conv)
{
    __shared__ __align__(16) short xh[49 * 256];   // 24.5 KiB
    __shared__ __align__(16) short xl[49 * 256];   // 24.5 KiB
    __shared__ float red[20];

    int t = threadIdx.x, m = blockIdx.x, b = m >> 9;
    const float* xg = bfq + (size_t)m * 12544 + (size_t)t * 49;

    // ---- stage x -> bf16 hi AND lo (all 13 loads issued unrolled) ----
    {
        float qs = 0.f;
#pragma unroll
        for (int r = 0; r < 12; ++r) {
            f4u v = *(const f4u*)&xg[r * 4];
#pragma unroll
            for (int j = 0; j < 4; ++j) {
                int hw = r * 4 + j;
                float x = v[j];
                qs += x;
                unsigned short hh = bf16_rne(x);
                int idx = (hw * 256 + t) ^ ((hw & 7) << 3);
                xh[idx] = (short)hh;
                xl[idx] = (short)bf16_rne(x - bf16_to_f(hh));
            }
        }
        float x48 = xg[48];
        qs += x48;
        unsigned short hh48 = bf16_rne(x48);
        xh[48 * 256 + t] = (short)hh48;            // 48&7 == 0 -> no xor
        xl[48 * 256 + t] = (short)bf16_rne(x48 - bf16_to_f(hh48));
        ws[WS_QMEAN + (size_t)m * 256 + t] = qs * (1.f / 49.f);
    }
    __syncthreads();

    int w = t >> 6, l = t & 63, cl = l & 15, g = l >> 4;

    f32x4 acc[5][4];
#pragma unroll
    for (int i = 0; i < 5; ++i)
#pragma unroll
        for (int nt = 0; nt < 4; ++nt) acc[i][nt] = (f32x4)0.f;

    const short* wfH = (const short*)(ws + WS_WFH);
    const short* wfL = (const short*)(ws + WS_WFL);

    int bcol[4];
#pragma unroll
    for (int nt = 0; nt < 4; ++nt) {
        int col = nt * 16 + cl;
        if (col >= 49) col = 0;
        bcol[nt] = col;
    }

    // ---- fused K-loop: acc += Wh*xh + Wh*xl + Wl*xh ----
#pragma unroll 1
    for (int ks = 0; ks < 8; ++ks) {
        short8 bh[4], bl[4];
#pragma unroll
        for (int nt = 0; nt < 4; ++nt) {
            int col = bcol[nt];
            int idx = (col * 256 + ks * 32 + g * 8) ^ ((col & 7) << 3);
            bh[nt] = *(const short8*)&xh[idx];
            bl[nt] = *(const short8*)&xl[idx];
        }
#pragma unroll
        for (int i = 0; i < 5; ++i) {
            int mt = w + 4 * i;
            size_t off = ((size_t)(mt * 8 + ks) * 64 + l) * 8;
            short8 ah = *(const short8*)&wfH[off];
            short8 al = *(const short8*)&wfL[off];
            acc[i][0] = __builtin_amdgcn_mfma_f32_16x16x32_bf16(ah, bh[0], acc[i][0], 0, 0, 0);
            acc[i][1] = __builtin_amdgcn_mfma_f32_16x16x32_bf16(ah, bh[1], acc[i][1], 0, 0, 0);
            acc[i][2] = __builtin_amdgcn_mfma_f32_16x16x32_bf16(ah, bh[2], acc[i][2], 0, 0, 0);
            acc[i][3] = __builtin_amdgcn_mfma_f32_16x16x32_bf16(ah, bh[3], acc[i][3], 0, 0, 0);
            acc[i][0] = __builtin_amdgcn_mfma_f32_16x16x32_bf16(ah, bl[0], acc[i][0], 0, 0, 0);
            acc[i][1] = __builtin_amdgcn_mfma_f32_16x16x32_bf16(ah, bl[1], acc[i][1], 0, 0, 0);
            acc[i][2] = __builtin_amdgcn_mfma_f32_16x16x32_bf16(ah, bl[2], acc[i][2], 0, 0, 0);
            acc[i][3] = __builtin_amdgcn_mfma_f32_16x16x32_bf16(ah, bl[3], acc[i][3], 0, 0, 0);
            acc[i][0] = __builtin_amdgcn_mfma_f32_16x16x32_bf16(al, bh[0], acc[i][0], 0, 0, 0);
            acc[i][1] = __builtin_amdgcn_mfma_f32_16x16x32_bf16(al, bh[1], acc[i][1], 0, 0, 0);
            acc[i][2] = __builtin_amdgcn_mfma_f32_16x16x32_bf16(al, bh[2], acc[i][2], 0, 0, 0);
            acc[i][3] = __builtin_amdgcn_mfma_f32_16x16x32_bf16(al, bh[3], acc[i][3], 0, 0, 0);
        }
    }

    // ---- corr epilogue ----
    float csum = 0.f;
    {
        const float* yb = ws + WS_YST + (size_t)b * 256 * 49;
#pragma unroll
        for (int i = 0; i < 4; ++i) {
            int row0 = (w + 4 * i) * 16 + g * 4;
#pragma unroll
            for (int q = 0; q < 4; ++q) {
                int row = row0 + q;
                float p = 0.f;
#pragma unroll
                for (int nt = 0; nt < 4; ++nt) {
                    int col = nt * 16 + cl;
                    if (col < 49) p += acc[i][nt][q] * yb[(size_t)row * 49 + col];
                }
                p += __shfl_xor(p, 1, 64);
                p += __shfl_xor(p, 2, 64);
                p += __shfl_xor(p, 4, 64);
                p += __shfl_xor(p, 8, 64);
                if (cl == 0) csum += fmaxf(p, 0.f) * scor_w[row];
            }
        }
    }
    __syncthreads();   // ALL waves done with MFMA B-reads; xh/xl reusable

    // ---- phase-2 overlays ----
    float* s1    = (float*)xh;                 // [64][52]   3328 floats
    float* sp1   = s1 + 64 * 52;               // [64][28]   1792 -> 5120
    float* sc2T  = s1 + 5120;                  // [9][64]    576  -> 5696 <= 6272
    float* cpart = (float*)xl;                 // [4][64][11] (VALU-conv path)

    // x1 epilogue: tile w+16 = W1q rows
    {
        const float* ub = ws + WS_UST + (size_t)b * 64 * 49;
        int ch0 = w * 16 + g * 4;
#pragma unroll
        for (int q = 0; q < 4; ++q) {
            int ch = ch0 + q;
#pragma unroll
            for (int nt = 0; nt < 4; ++nt) {
                int col = nt * 16 + cl;
                if (col < 49)
                    s1[ch * 52 + col] = fmaxf(acc[4][nt][q] + ub[(size_t)ch * 49 + col], 0.f);
            }
        }
    }
    __syncthreads();

    // avgpool3 7x7 -> 5x5, padded [64][28]
    for (int i = t; i < 64 * 25; i += 256) {
        int ch = i / 25, pos = i - ch * 25;
        int py = pos / 5, px = pos - py * 5;
        const float* base = s1 + ch * 52 + py * 7 + px;
        float s = base[0] + base[1] + base[2]
                + base[7] + base[8] + base[9]
                + base[14] + base[15] + base[16];
        sp1[ch * 28 + pos] = s * (1.f / 9.f);
    }
    __syncthreads();

    if (use_mfma_conv) {
        // ---- conv as MFMA: im2col bimT[9][576] bf16 hi/lo in xl region ----
        short* bimh = (short*)xl;              // 5184 shorts
        short* biml = ((short*)xl) + 5184;     // 16B-aligned (10368 B offset)
#pragma unroll 1
        for (int kk = t; kk < 576; kk += 256) {
            int ic = kk / 9;
            int k  = kk - ic * 9;
            int ky = k / 3, kx = k - ky * 3;
            const float* bsp = sp1 + ic * 28 + ky * 5 + kx;
#pragma unroll
            for (int py = 0; py < 3; ++py)
#pragma unroll
                for (int px = 0; px < 3; ++px) {
                    int pos = py * 3 + px;
                    float v = bsp[py * 5 + px];
                    unsigned short hh = bf16_rne(v);
                    int idx = pos * 576 + (kk ^ ((pos & 7) << 3));
                    bimh[idx] = (short)hh;
                    biml[idx] = (short)bf16_rne(v - bf16_to_f(hh));
                }
        }
        __syncthreads();

        f32x4 a2 = (f32x4)0.f;
        const short* w2h = (const short*)(ws + WS_W2FH);
        const short* w2l = (const short*)(ws + WS_W2FL);
        int c9 = (cl < 9) ? cl : 0;
        int bbase = c9 * 576, bxor = (c9 & 7) << 3;
#pragma unroll 1
        for (int ks2 = 0; ks2 < 18; ++ks2) {
            int bidx = bbase + ((ks2 * 32 + g * 8) ^ bxor);
            short8 bh = *(const short8*)&bimh[bidx];
            short8 bl = *(const short8*)&biml[bidx];
            size_t off = ((size_t)(w * 18 + ks2) * 64 + l) * 8;
            short8 ah = *(const short8*)&w2h[off];
            short8 al = *(const short8*)&w2l[off];
            a2 = __builtin_amdgcn_mfma_f32_16x16x32_bf16(ah, bh, a2, 0, 0, 0);
            a2 = __builtin_amdgcn_mfma_f32_16x16x32_bf16(ah, bl, a2, 0, 0, 0);
            a2 = __builtin_amdgcn_mfma_f32_16x16x32_bf16(al, bh, a2, 0, 0, 0);
        }
        if (cl < 9) {
#pragma unroll
            for (int q = 0; q < 4; ++q)
                sc2T[cl * 64 + (w * 16 + g * 4 + q)] = fmaxf(a2[q], 0.f);
        }
        __syncthreads();
    } else {
        // ---- proven VALU broadcast conv (fallback) ----
        {
            int oc = t & 63, icq = t >> 6;
            float a9[9] = {0,0,0,0,0,0,0,0,0};
            const float* wb2 = W2 + (size_t)oc * 576 + icq * 16 * 9;
#pragma unroll 1
            for (int ic16 = 0; ic16 < 16; ++ic16) {
                int ic = icq * 16 + ic16;
                const f4* ar = (const f4*)(sp1 + ic * 28);
                float av[28];
                *(f4*)&av[0]  = ar[0];
                *(f4*)&av[4]  = ar[1];
                *(f4*)&av[8]  = ar[2];
                *(f4*)&av[12] = ar[3];
                *(f4*)&av[16] = ar[4];
                *(f4*)&av[20] = ar[5];
                *(f4*)&av[24] = ar[6];
                const float* wi = wb2 + ic16 * 9;
                f4u w0 = *(const f4u*)wi;
                f4u w1 = *(const f4u*)(wi + 4);
                float wv[9] = { w0[0], w0[1], w0[2], w0[3], w1[0], w1[1], w1[2], w1[3], wi[8] };
#pragma unroll
                for (int py = 0; py < 3; ++py)
#pragma unroll
                    for (int px = 0; px < 3; ++px) {
                        int p9 = py * 3 + px;
#pragma unroll
                        for (int ky = 0; ky < 3; ++ky)
#pragma unroll
                            for (int kx = 0; kx < 3; ++kx)
                                a9[p9] = fmaf(wv[ky * 3 + kx],
                                              av[(py + ky) * 5 + (px + kx)], a9[p9]);
                    }
            }
#pragma unroll
            for (int p = 0; p < 9; ++p)
                cpart[((size_t)(t >> 6) * 64 + (t & 63)) * 11 + p] = a9[p];
        }
        __syncthreads();
        for (int i = t; i < 576; i += 256) {
            int pos = i >> 6, occ = i & 63;
            float s = cpart[((size_t)0 * 64 + occ) * 11 + pos]
                    + cpart[((size_t)1 * 64 + occ) * 11 + pos]
                    + cpart[((size_t)2 * 64 + occ) * 11 + pos]
                    + cpart[((size_t)3 * 64 + occ) * 11 + pos];
            sc2T[pos * 64 + occ] = fmaxf(s, 0.f);
        }
        __syncthreads();
    }

    // ---- W3 (256x64) + relu + avgpool3 3x3 -> 1 (broadcast f4 reads) ----
    float xfin;
    {
        float xw[9] = {0,0,0,0,0,0,0,0,0};
        const f4* wr = (const f4*)(W3 + (size_t)t * 64);
#pragma unroll 1
        for (int gg = 0; gg < 16; ++gg) {
            f4 wv4 = wr[gg];
#pragma unroll
            for (int p = 0; p < 9; ++p) {
                f4 c = *(const f4*)(sc2T + p * 64 + gg * 4);
                xw[p] = fmaf(wv4[0], c[0], xw[p]);
                xw[p] = fmaf(wv4[1], c[1], xw[p]);
                xw[p] = fmaf(wv4[2], c[2], xw[p]);
                xw[p] = fmaf(wv4[3], c[3], xw[p]);
            }
        }
        float s = 0.f;
#pragma unroll
        for (int p = 0; p < 9; ++p) s += fmaxf(xw[p], 0.f);
        xfin = s * (1.f / 9.f);
    }

    // ---- merged 5-way block reduction: ONE barrier ----
    float v0 = xfin * spr_w[t] + csum;
    float v1 = xfin * dpr_w[0 * 256 + t];
    float v2 = xfin * dpr_w[1 * 256 + t];
    float v3 = xfin * dpr_w[2 * 256 + t];
    float v4 = xfin * dpr_w[3 * 256 + t];
#pragma unroll
    for (int off = 32; off > 0; off >>= 1) {
        v0 += __shfl_xor(v0, off, 64);
        v1 += __shfl_xor(v1, off, 64);
        v2 += __shfl_xor(v2, off, 64);
        v3 += __shfl_xor(v3, off, 64);
        v4 += __shfl_xor(v4, off, 64);
    }
    if (l == 0) {
        red[w * 5 + 0] = v0; red[w * 5 + 1] = v1; red[w * 5 + 2] = v2;
        red[w * 5 + 3] = v3; red[w * 5 + 4] = v4;
    }
    __syncthreads();

    if (t == 0) {
        float r_s  = red[0] + red[5] + red[10] + red[15];
        float r_d0 = red[1] + red[6] + red[11] + red[16];
        float r_d1 = red[2] + red[7] + red[12] + red[17];
        float r_d2 = red[3] + red[8] + red[13] + red[18];
        float r_d3 = red[4] + red[9] + red[14] + red[19];

        ws[WS_SP + m] = r_s + spr_b[0] + scor_b[0];

        float d0 = r_d0 + dpr_b[0];
        float d1 = r_d1 + dpr_b[1];
        float d2 = fminf(r_d2 + dpr_b[2], 4.135166556742356f);
        float d3 = fminf(r_d3 + dpr_b[3], 4.135166556742356f);

        const float* pr = proposals + (size_t)m * 4;
        float x1p = pr[0], y1p = pr[1], x2p = pr[2], y2p = pr[3];
        float wd = x2p - x1p, hd = y2p - y1p;
        float cx = x1p + 0.5f * wd, cy = y1p + 0.5f * hd;
        float pcx = d0 * wd + cx, pcy = d1 * hd + cy;
        float pw = expf(d2) * wd, ph = expf(d3) * hd;
        float Wf = (float)image_size[1];
        float Hf = (float)image_size[0];
        out[(size_t)m * 4 + 0] = fminf(fmaxf(pcx - 0.5f * pw, 0.f), Wf);
        out[(size_t)m * 4 + 1] = fminf(fmaxf(pcy - 0.5f * ph, 0.f), Hf);
        out[(size_t)m * 4 + 2] = fminf(fmaxf(pcx + 0.5f * pw, 0.f), Wf);
        out[(size_t)m * 4 + 3] = fminf(fmaxf(pcy + 0.5f * ph, 0.f), Hf);
    }
}

// ---------------------------------------------------------------------------
// K3: FC path, 16 m's per block. grid = 256, block = 256.
// ---------------------------------------------------------------------------
__global__ __launch_bounds__(256) void k_fc(
    const float* __restrict__ fc1_w, const float* __restrict__ fc1_b,
    const float* __restrict__ fc2_w, const float* __restrict__ fc2_b,
    const float* __restrict__ sfc_w, const float* __restrict__ sfc_b,
    float* __restrict__ ws, float* __restrict__ out)
{
    __shared__ __align__(16) float sxfc[16][512];
    __shared__ __align__(16) float sh1[16][256];
    __shared__ float s_red[64];
    int t = threadIdx.x;
    int m0 = blockIdx.x * 16;
    int w = t >> 6, l = t & 63;

#pragma unroll
    for (int mi = 0; mi < 16; ++mi) {
        int mg = m0 + mi;
        int b = mg >> 9;
        sxfc[mi][t]       = ws[WS_QMEAN + (size_t)mg * 256 + t];
        sxfc[mi][256 + t] = ws[WS_SMEAN + (size_t)b * 256 + t];
    }
    __syncthreads();

    {
        const f4* wr = (const f4*)(fc1_w + t * 512);
        float acc[16];
#pragma unroll
        for (int mi = 0; mi < 16; ++mi) acc[mi] = 0.f;
#pragma unroll 1
        for (int k4 = 0; k4 < 128; ++k4) {
            f4 wv = wr[k4];
#pragma unroll
            for (int mi = 0; mi < 16; ++mi) {
                f4 x = ((const f4*)sxfc[mi])[k4];
                acc[mi] = fmaf(wv[0], x[0], acc[mi]);
                acc[mi] = fmaf(wv[1], x[1], acc[mi]);
                acc[mi] = fmaf(wv[2], x[2], acc[mi]);
                acc[mi] = fmaf(wv[3], x[3], acc[mi]);
            }
        }
        float bb = fc1_b[t];
#pragma unroll
        for (int mi = 0; mi < 16; ++mi) sh1[mi][t] = fmaxf(acc[mi] + bb, 0.f);
    }
    __syncthreads();

    float val[16];
    {
        const f4* wr = (const f4*)(fc2_w + t * 256);
        float acc[16];
#pragma unroll
        for (int mi = 0; mi < 16; ++mi) acc[mi] = 0.f;
#pragma unroll 1
        for (int k4 = 0; k4 < 64; ++k4) {
            f4 wv = wr[k4];
#pragma unroll
            for (int mi = 0; mi < 16; ++mi) {
                f4 x = ((const f4*)sh1[mi])[k4];
                acc[mi] = fmaf(wv[0], x[0], acc[mi]);
                acc[mi] = fmaf(wv[1], x[1], acc[mi]);
                acc[mi] = fmaf(wv[2], x[2], acc[mi]);
                acc[mi] = fmaf(wv[3], x[3], acc[mi]);
            }
        }
        float bb = fc2_b[t];
        float sw = sfc_w[t];
#pragma unroll
        for (int mi = 0; mi < 16; ++mi) val[mi] = sw * fmaxf(acc[mi] + bb, 0.f);
    }

#pragma unroll
    for (int mi = 0; mi < 16; ++mi) {
        float v = val[mi];
#pragma unroll
        for (int off = 32; off > 0; off >>= 1) v += __shfl_xor(v, off, 64);
        if (l == 0) s_red[w * 16 + mi] = v;
    }
    __syncthreads();

    if (t < 16) {
        float r = s_red[0 * 16 + t] + s_red[1 * 16 + t]
                + s_red[2 * 16 + t] + s_red[3 * 16 + t];
        float tot = ws[WS_SP + m0 + t] + (r + sfc_b[0]);
        out[OUT_SCORES + m0 + t] = 1.0f / (1.0f + expf(-tot));
    }
}

// ---------------------------------------------------------------------------
// K4: fused NMS (sort + IoU mask + greedy + scatter), all in LDS.
// grid = 8, block = 1024 (16 waves). ~46 KB LDS.
// ---------------------------------------------------------------------------
__global__ __launch_bounds__(1024) void k_nms(float* __restrict__ out)
{
    __shared__ float ssc[512];
    __shared__ __align__(16) float sbox[512 * 4];
    __shared__ float sarea[512];
    __shared__ int   sidx[512];
    __shared__ unsigned long long smask[512 * 8];   // 32 KB

    int t = threadIdx.x, b = blockIdx.x;
    int wv = t >> 6, lane = t & 63;
    const float* sc_g = out + OUT_SCORES + (size_t)b * 512;

    if (t < 512) ssc[t] = sc_g[t];
    __syncthreads();

    if (t < 512) {
        float si = ssc[t];
        int r = 0;
        for (int j = 0; j < 512; ++j) {
            float sj = ssc[j];
            r += (int)((sj > si) || (sj == si && j < t));
        }
        f4 v = *(const f4*)(out + ((size_t)b * 512 + t) * 4);
        *(f4*)&sbox[r * 4] = v;
        sarea[r] = fmaxf(v[2] - v[0], 0.f) * fmaxf(v[3] - v[1], 0.f);
        sidx[r] = t;
    }
    __syncthreads();

    // IoU bitmask: 16 waves x 32 rows
#pragma unroll 1
    for (int k = 0; k < 32; ++k) {
        int i = wv * 32 + k;
        f4 bi = *(const f4*)&sbox[i * 4];
        float ai = sarea[i];
#pragma unroll
        for (int w8 = 0; w8 < 8; ++w8) {
            int j = w8 * 64 + lane;
            f4 bj = *(const f4*)&sbox[j * 4];
            float aj = sarea[j];
            float xx1 = fmaxf(bi[0], bj[0]), yy1 = fmaxf(bi[1], bj[1]);
            float xx2 = fminf(bi[2], bj[2]), yy2 = fminf(bi[3], bj[3]);
            float inter = fmaxf(xx2 - xx1, 0.f) * fmaxf(yy2 - yy1, 0.f);
            float iou = inter / fmaxf(ai + aj - inter, 1e-9f);
            bool sup = (iou > 0.5f) && (j > i);
            unsigned long long bal = __ballot(sup);
            if (lane == 0) smask[i * 8 + w8] = bal;
        }
    }
    __syncthreads();

    if (wv == 0) {
        unsigned long long kw = ~0ull;
        unsigned long long nxt = (lane < 8) ? smask[lane] : 0ull;
        for (int i = 0; i < 512; ++i) {
            unsigned long long cur = nxt;
            if (i < 511 && lane < 8) nxt = smask[(size_t)(i + 1) * 8 + lane];
            unsigned long long wi = __shfl(kw, i >> 6, 64);
            if ((wi >> (i & 63)) & 1ull) {
                if (lane < 8) kw &= ~cur;
            }
        }
        if (lane < 8) smask[lane] = kw;
    }
    __syncthreads();

    if (t < 512) {
        unsigned long long word = smask[t >> 6];
        out[OUT_KEEP + (size_t)b * 512 + sidx[t]] =
            ((word >> (t & 63)) & 1ull) ? 1.0f : 0.0f;
    }
}

// ---------------------------------------------------------------------------
extern "C" void kernel_launch(void* const* d_in, const int* in_sizes, int n_in,
                              void* d_out, int out_size, void* d_ws, size_t ws_size,
                              hipStream_t stream) {
    const float* bfq       = (const float*)d_in[0];
    const float* bfs       = (const float*)d_in[1];
    const float* proposals = (const float*)d_in[2];
    const int*   image_sz  = (const int*)d_in[3];
    const float* W1        = (const float*)d_in[4];
    const float* W2        = (const float*)d_in[5];
    const float* W3        = (const float*)d_in[6];
    const float* Wcor      = (const float*)d_in[7];
    const float* fc1_w     = (const float*)d_in[8];
    const float* fc1_b     = (const float*)d_in[9];
    const float* fc2_w     = (const float*)d_in[10];
    const float* fc2_b     = (const float*)d_in[11];
    const float* sfc_w     = (const float*)d_in[12];
    const float* sfc_b     = (const float*)d_in[13];
    const float* scor_w    = (const float*)d_in[14];
    const float* scor_b    = (const float*)d_in[15];
    const float* spr_w     = (const float*)d_in[16];
    const float* spr_b     = (const float*)d_in[17];
    const float* dpr_w     = (const float*)d_in[18];
    const float* dpr_b     = (const float*)d_in[19];
    float* out = (float*)d_out;
    float* ws  = (float*)d_ws;

    int big = (ws_size >= WS_NEED_BIG * sizeof(float)) ? 1 : 0;

    k_prep<<<big ? 122 : 104, 256, 0, stream>>>(bfs, Wcor, W1, W2, ws, big);
    k_heavy<<<NM, 256, 0, stream>>>(bfq, W2, W3,
                                    scor_w, scor_b, spr_w, spr_b,
                                    dpr_w, dpr_b, proposals, image_sz, ws, out, big);
    k_fc<<<NM / 16, 256, 0, stream>>>(fc1_w, fc1_b, fc2_w, fc2_b,
                                      sfc_w, sfc_b, ws, out);
    k_nms<<<NB, 1024, 0, stream>>>(out);
}

// Round 17
// 411.641 us; speedup vs baseline: 2.7951x; 1.0887x over previous
//
#include <hip/hip_runtime.h>
#include <math.h>

typedef float f4 __attribute__((ext_vector_type(4)));
typedef f4 f4u __attribute__((aligned(4)));   // 4B-aligned vector load
typedef float f32x4 __attribute__((ext_vector_type(4)));
typedef short short8 __attribute__((ext_vector_type(8)));

constexpr int NB  = 8;
constexpr int NN  = 512;
constexpr int NC  = 256;
constexpr int NHW = 49;
constexpr int NM  = NB * NN;   // 4096
constexpr int XS  = 260;       // k_prep transposed x row stride (floats)

// ---- workspace layout (float offsets) ----
constexpr size_t WS_SMEAN = 0;                        // 8*256              -> 2048
constexpr size_t WS_YST   = 2048;                     // 8*256*49           -> 102400
constexpr size_t WS_UST   = 102400;                   // 8*64*49            -> 127488
constexpr size_t WS_WFH   = 127488;                   // 20*8*64*8 bf16     -> 168448
constexpr size_t WS_WFL   = 168448;                   // same (lo part)     -> 209408
constexpr size_t WS_SP    = 209408;                   // 4096               -> 213504
constexpr size_t WS_QMEAN = 213504;                   // 4096*256           -> 1262080
// W2 MFMA fragments (guard: ws >= WS_NEED_BIG floats):
constexpr size_t WS_W2FH  = 1262080;                  // 4*18*64*8 bf16 = 18432 f
constexpr size_t WS_W2FL  = 1280512;                  // -> 1298944
constexpr size_t WS_NEED_BIG = 1298944;
// FC MFMA fragments (guard: ws >= WS_NEED_BIG2 floats):
constexpr size_t WS_F1H   = 1298944;                  // 256*512 bf16 = 65536 f
constexpr size_t WS_F1L   = 1364480;                  // 65536 f
constexpr size_t WS_F2H   = 1430016;                  // 256*256 bf16 = 32768 f
constexpr size_t WS_F2L   = 1462784;                  // -> 1495552
constexpr size_t WS_NEED_BIG2 = 1495552;

// ---- output layout (floats): boxes[4096*4] | scores[4096] | keep[4096] ----
constexpr size_t OUT_SCORES = (size_t)NM * 4;
constexpr size_t OUT_KEEP   = OUT_SCORES + NM;

__device__ __forceinline__ unsigned short bf16_rne(float f) {
    unsigned u = __float_as_uint(f);
    return (unsigned short)((u + 0x7FFFu + ((u >> 16) & 1u)) >> 16);
}
__device__ __forceinline__ float bf16_to_f(unsigned short h) {
    return __uint_as_float(((unsigned)h) << 16);
}

// stage x [256][49] (global) -> LDS transposed [49][XS] f32 (k_prep only)
__device__ __forceinline__ void stage_xT(const float* __restrict__ g, float* sx, int t) {
#pragma unroll
    for (int rep = 0; rep < 13; ++rep) {
        int id = rep * 256 + t;
        if (id < 3136) {
            int c4 = id / 49;
            int hw = id - c4 * 49;
            f4 v;
            v[0] = g[(c4 * 4 + 0) * 49 + hw];
            v[1] = g[(c4 * 4 + 1) * 49 + hw];
            v[2] = g[(c4 * 4 + 2) * 49 + hw];
            v[3] = g[(c4 * 4 + 3) * 49 + hw];
            *(f4*)&sx[hw * XS + c4 * 4] = v;
        }
    }
}

// split-bf16 fragment build helper: src row-major [.. x K], frag dst
__device__ __forceinline__ void build_frag(
    const float* __restrict__ src, short* __restrict__ dh,
    short* __restrict__ dl)
{
#pragma unroll
    for (int j = 0; j < 8; ++j) {
        float v = src[j];
        unsigned short hh = bf16_rne(v);
        dh[j] = (short)hh;
        dl[j] = (short)bf16_rne(v - bf16_to_f(hh));
    }
}

// ---------------------------------------------------------------------------
// K1: merged prep. grid = 104 / 122 / 218, block = 256.
//  0..63    : per-batch precompute (y_s / u_s / smean)
//  64..103  : [Wcor;W1q] fragments
//  104..121 : W2 fragments (big)
//  122..185 : fc1 fragments (big2)
//  186..217 : fc2 fragments (big2)
// ---------------------------------------------------------------------------
__global__ __launch_bounds__(256, 2) void k_prep(
    const float* __restrict__ bfs, const float* __restrict__ Wcor,
    const float* __restrict__ W1, const float* __restrict__ W2,
    const float* __restrict__ fc1_w, const float* __restrict__ fc2_w,
    float* __restrict__ ws, int big, int big2)
{
    int t = threadIdx.x, blk = blockIdx.x;

    if (blk >= 186) {                     // fc2 fragments: 128 groups
        if (!big2) return;
        int fb = (blk - 186) * 4 + (t >> 6);
        int l = t & 63;
        int mt = fb >> 3, ks = fb & 7;
        int row = mt * 16 + (l & 15);
        int k0 = ks * 32 + (l >> 4) * 8;
        build_frag(fc2_w + (size_t)row * 256 + k0,
                   (short*)(ws + WS_F2H) + ((size_t)fb * 64 + l) * 8,
                   (short*)(ws + WS_F2L) + ((size_t)fb * 64 + l) * 8);
        return;
    }
    if (blk >= 122) {                     // fc1 fragments: 256 groups
        if (!big2) return;
        int fb = (blk - 122) * 4 + (t >> 6);
        int l = t & 63;
        int mt = fb >> 4, ks = fb & 15;
        int row = mt * 16 + (l & 15);
        int k0 = ks * 32 + (l >> 4) * 8;
        build_frag(fc1_w + (size_t)row * 512 + k0,
                   (short*)(ws + WS_F1H) + ((size_t)fb * 64 + l) * 8,
                   (short*)(ws + WS_F1L) + ((size_t)fb * 64 + l) * 8);
        return;
    }
    if (blk >= 104) {                     // W2 fragments
        if (!big) return;
        int ks2 = blk - 104;              // 0..17
        int mt = t >> 6, l = t & 63;
        int row = mt * 16 + (l & 15);
        int kk0 = ks2 * 32 + (l >> 4) * 8;
        build_frag(W2 + (size_t)row * 576 + kk0,
                   (short*)(ws + WS_W2FH) + ((size_t)(mt * 18 + ks2) * 64 + l) * 8,
                   (short*)(ws + WS_W2FL) + ((size_t)(mt * 18 + ks2) * 64 + l) * 8);
        return;
    }
    if (blk >= 64) {                      // [Wcor;W1q] fragments
        int ob = (blk - 64) * 4 + (t >> 6);
        int l = t & 63;
        int mt = ob >> 3, ks = ob & 7;
        int row = mt * 16 + (l & 15);
        int k0 = ks * 32 + (l >> 4) * 8;
        const float* src = (row < 256) ? (Wcor + (size_t)row * 256 + k0)
                                       : (W1 + (size_t)(row - 256) * 512 + k0);
        build_frag(src,
                   (short*)(ws + WS_WFH) + ((size_t)ob * 64 + l) * 8,
                   (short*)(ws + WS_WFL) + ((size_t)ob * 64 + l) * 8);
        return;
    }

    __shared__ __align__(16) float smem[49 * XS + 16];
    float* sx = smem;
    int b = blk >> 3;
    int og8 = blk & 7;

    stage_xT(bfs + (size_t)b * 12544, sx, t);
    __syncthreads();

    if (og8 == 0) {
        float s = 0.f;
        for (int hw = 0; hw < 49; ++hw) s += sx[hw * XS + t];
        ws[WS_SMEAN + (size_t)b * 256 + t] = s * (1.f / 49.f);
    }

    int og2 = t >> 3, hwg = t & 7;
    int hwb = (hwg == 7) ? 0 : hwg * 7;
    int oA = og8 * 32 + og2;
    bool do_u = (og8 < 2);
    int o2 = og8 * 32 + og2;

    float acc0[7] = {0,0,0,0,0,0,0};
    float a1a[7]  = {0,0,0,0,0,0,0};
    const float* xrow = sx + hwb * XS;
    const float* w0r = Wcor + (size_t)oA * 256;
    const float* war = W1 + (size_t)o2 * 512 + 256;

#pragma unroll 1
    for (int c4 = 0; c4 < 64; ++c4) {
        f4 xv[7];
#pragma unroll
        for (int i = 0; i < 7; ++i) xv[i] = *(const f4*)&xrow[i * XS + c4 * 4];
        f4 w0 = *(const f4*)&w0r[c4 * 4];
        f4 wa = *(const f4*)&war[c4 * 4];
#pragma unroll
        for (int j = 0; j < 4; ++j) {
#pragma unroll
            for (int i = 0; i < 7; ++i) {
                float x = xv[i][j];
                acc0[i] = fmaf(w0[j], x, acc0[i]);
                a1a[i]  = fmaf(wa[j], x, a1a[i]);
            }
        }
    }

    if (hwg < 7) {
#pragma unroll
        for (int i = 0; i < 7; ++i) {
            int hw = hwb + i;
            ws[WS_YST + ((size_t)b * 256 + oA) * 49 + hw] = acc0[i];
            if (do_u)
                ws[WS_UST + ((size_t)b * 64 + o2) * 49 + hw] = a1a[i];
        }
    }
}

// ---------------------------------------------------------------------------
// K2: heavy per-m kernel. MFMA fused K-loop; MFMA conv (big) with PADDED
// im2col rows (584 shorts: 576%128B==0 caused ~9-way conv B-read conflicts).
// ---------------------------------------------------------------------------
constexpr int IMR = 584;    // padded im2col row stride (shorts)

__global__ __launch_bounds__(256, 3) void k_heavy(
    const float* __restrict__ bfq,
    const float* __restrict__ W2, const float* __restrict__ W3,
    const float* __restrict__ scor_w, const float* __restrict__ scor_b,
    const float* __restrict__ spr_w, const float* __restrict__ spr_b,
    const float* __restrict__ dpr_w, const float* __restrict__ dpr_b,
    const float* __restrict__ proposals, const int* __restrict__ image_size,
    float* __restrict__ ws, float* __restrict__ out, int use_mfma_conv)
{
    __shared__ __align__(16) short xh[49 * 256];   // 24.5 KiB
    __shared__ __align__(16) short xl[49 * 256];   // 24.5 KiB
    __shared__ float red[20];

    int t = threadIdx.x, m = blockIdx.x, b = m >> 9;
    const float* xg = bfq + (size_t)m * 12544 + (size_t)t * 49;

    // ---- stage x -> bf16 hi AND lo (all 13 loads issued unrolled) ----
    {
        float qs = 0.f;
#pragma unroll
        for (int r = 0; r < 12; ++r) {
            f4u v = *(const f4u*)&xg[r * 4];
#pragma unroll
            for (int j = 0; j < 4; ++j) {
                int hw = r * 4 + j;
                float x = v[j];
                qs += x;
                unsigned short hh = bf16_rne(x);
                int idx = (hw * 256 + t) ^ ((hw & 7) << 3);
                xh[idx] = (short)hh;
                xl[idx] = (short)bf16_rne(x - bf16_to_f(hh));
            }
        }
        float x48 = xg[48];
        qs += x48;
        unsigned short hh48 = bf16_rne(x48);
        xh[48 * 256 + t] = (short)hh48;            // 48&7 == 0 -> no xor
        xl[48 * 256 + t] = (short)bf16_rne(x48 - bf16_to_f(hh48));
        ws[WS_QMEAN + (size_t)m * 256 + t] = qs * (1.f / 49.f);
    }
    __syncthreads();

    int w = t >> 6, l = t & 63, cl = l & 15, g = l >> 4;

    f32x4 acc[5][4];
#pragma unroll
    for (int i = 0; i < 5; ++i)
#pragma unroll
        for (int nt = 0; nt < 4; ++nt) acc[i][nt] = (f32x4)0.f;

    const short* wfH = (const short*)(ws + WS_WFH);
    const short* wfL = (const short*)(ws + WS_WFL);

    int bcol[4];
#pragma unroll
    for (int nt = 0; nt < 4; ++nt) {
        int col = nt * 16 + cl;
        if (col >= 49) col = 0;
        bcol[nt] = col;
    }

    // ---- fused K-loop: acc += Wh*xh + Wh*xl + Wl*xh ----
#pragma unroll 1
    for (int ks = 0; ks < 8; ++ks) {
        short8 bh[4], bl[4];
#pragma unroll
        for (int nt = 0; nt < 4; ++nt) {
            int col = bcol[nt];
            int idx = (col * 256 + ks * 32 + g * 8) ^ ((col & 7) << 3);
            bh[nt] = *(const short8*)&xh[idx];
            bl[nt] = *(const short8*)&xl[idx];
        }
#pragma unroll
        for (int i = 0; i < 5; ++i) {
            int mt = w + 4 * i;
            size_t off = ((size_t)(mt * 8 + ks) * 64 + l) * 8;
            short8 ah = *(const short8*)&wfH[off];
            short8 al = *(const short8*)&wfL[off];
            acc[i][0] = __builtin_amdgcn_mfma_f32_16x16x32_bf16(ah, bh[0], acc[i][0], 0, 0, 0);
            acc[i][1] = __builtin_amdgcn_mfma_f32_16x16x32_bf16(ah, bh[1], acc[i][1], 0, 0, 0);
            acc[i][2] = __builtin_amdgcn_mfma_f32_16x16x32_bf16(ah, bh[2], acc[i][2], 0, 0, 0);
            acc[i][3] = __builtin_amdgcn_mfma_f32_16x16x32_bf16(ah, bh[3], acc[i][3], 0, 0, 0);
            acc[i][0] = __builtin_amdgcn_mfma_f32_16x16x32_bf16(ah, bl[0], acc[i][0], 0, 0, 0);
            acc[i][1] = __builtin_amdgcn_mfma_f32_16x16x32_bf16(ah, bl[1], acc[i][1], 0, 0, 0);
            acc[i][2] = __builtin_amdgcn_mfma_f32_16x16x32_bf16(ah, bl[2], acc[i][2], 0, 0, 0);
            acc[i][3] = __builtin_amdgcn_mfma_f32_16x16x32_bf16(ah, bl[3], acc[i][3], 0, 0, 0);
            acc[i][0] = __builtin_amdgcn_mfma_f32_16x16x32_bf16(al, bh[0], acc[i][0], 0, 0, 0);
            acc[i][1] = __builtin_amdgcn_mfma_f32_16x16x32_bf16(al, bh[1], acc[i][1], 0, 0, 0);
            acc[i][2] = __builtin_amdgcn_mfma_f32_16x16x32_bf16(al, bh[2], acc[i][2], 0, 0, 0);
            acc[i][3] = __builtin_amdgcn_mfma_f32_16x16x32_bf16(al, bh[3], acc[i][3], 0, 0, 0);
        }
    }

    // ---- corr epilogue ----
    float csum = 0.f;
    {
        const float* yb = ws + WS_YST + (size_t)b * 256 * 49;
#pragma unroll
        for (int i = 0; i < 4; ++i) {
            int row0 = (w + 4 * i) * 16 + g * 4;
#pragma unroll
            for (int q = 0; q < 4; ++q) {
                int row = row0 + q;
                float p = 0.f;
#pragma unroll
                for (int nt = 0; nt < 4; ++nt) {
                    int col = nt * 16 + cl;
                    if (col < 49) p += acc[i][nt][q] * yb[(size_t)row * 49 + col];
                }
                p += __shfl_xor(p, 1, 64);
                p += __shfl_xor(p, 2, 64);
                p += __shfl_xor(p, 4, 64);
                p += __shfl_xor(p, 8, 64);
                if (cl == 0) csum += fmaxf(p, 0.f) * scor_w[row];
            }
        }
    }
    __syncthreads();   // ALL waves done with MFMA B-reads; xh/xl reusable

    // ---- phase-2 overlays ----
    float* s1    = (float*)xh;                 // [64][52]   3328 floats
    float* sp1   = s1 + 64 * 52;               // [64][28]   1792 -> 5120
    float* sc2T  = s1 + 5120;                  // [9][64]    576  -> 5696 <= 6272
    float* cpart = (float*)xl;                 // VALU-conv path scratch

    // x1 epilogue: tile w+16 = W1q rows
    {
        const float* ub = ws + WS_UST + (size_t)b * 64 * 49;
        int ch0 = w * 16 + g * 4;
#pragma unroll
        for (int q = 0; q < 4; ++q) {
            int ch = ch0 + q;
#pragma unroll
            for (int nt = 0; nt < 4; ++nt) {
                int col = nt * 16 + cl;
                if (col < 49)
                    s1[ch * 52 + col] = fmaxf(acc[4][nt][q] + ub[(size_t)ch * 49 + col], 0.f);
            }
        }
    }
    __syncthreads();

    // avgpool3 7x7 -> 5x5, padded [64][28]
    for (int i = t; i < 64 * 25; i += 256) {
        int ch = i / 25, pos = i - ch * 25;
        int py = pos / 5, px = pos - py * 5;
        const float* base = s1 + ch * 52 + py * 7 + px;
        float s = base[0] + base[1] + base[2]
                + base[7] + base[8] + base[9]
                + base[14] + base[15] + base[16];
        sp1[ch * 28 + pos] = s * (1.f / 9.f);
    }
    __syncthreads();

    if (use_mfma_conv) {
        // ---- conv as MFMA: padded im2col bimT[9][IMR] bf16 hi/lo ----
        short* bimh = (short*)xl;                  // 9*IMR shorts
        short* biml = ((short*)xl) + 9 * IMR;      // 16B-aligned
#pragma unroll 1
        for (int kk = t; kk < 576; kk += 256) {
            int ic = kk / 9;
            int k  = kk - ic * 9;
            int ky = k / 3, kx = k - ky * 3;
            const float* bsp = sp1 + ic * 28 + ky * 5 + kx;
#pragma unroll
            for (int py = 0; py < 3; ++py)
#pragma unroll
                for (int px = 0; px < 3; ++px) {
                    int pos = py * 3 + px;
                    float v = bsp[py * 5 + px];
                    unsigned short hh = bf16_rne(v);
                    int idx = pos * IMR + (kk ^ ((pos & 7) << 3));
                    bimh[idx] = (short)hh;
                    biml[idx] = (short)bf16_rne(v - bf16_to_f(hh));
                }
        }
        __syncthreads();

        f32x4 a2 = (f32x4)0.f;
        const short* w2h = (const short*)(ws + WS_W2FH);
        const short* w2l = (const short*)(ws + WS_W2FL);
        int c9 = (cl < 9) ? cl : 0;
        int bbase = c9 * IMR, bxor = (c9 & 7) << 3;
#pragma unroll 1
        for (int ks2 = 0; ks2 < 18; ++ks2) {
            int bidx = bbase + ((ks2 * 32 + g * 8) ^ bxor);
            short8 bh = *(const short8*)&bimh[bidx];
            short8 bl = *(const short8*)&biml[bidx];
            size_t off = ((size_t)(w * 18 + ks2) * 64 + l) * 8;
            short8 ah = *(const short8*)&w2h[off];
            short8 al = *(const short8*)&w2l[off];
            a2 = __builtin_amdgcn_mfma_f32_16x16x32_bf16(ah, bh, a2, 0, 0, 0);
            a2 = __builtin_amdgcn_mfma_f32_16x16x32_bf16(ah, bl, a2, 0, 0, 0);
            a2 = __builtin_amdgcn_mfma_f32_16x16x32_bf16(al, bh, a2, 0, 0, 0);
        }
        if (cl < 9) {
#pragma unroll
            for (int q = 0; q < 4; ++q)
                sc2T[cl * 64 + (w * 16 + g * 4 + q)] = fmaxf(a2[q], 0.f);
        }
        __syncthreads();
    } else {
        {
            int oc = t & 63, icq = t >> 6;
            float a9[9] = {0,0,0,0,0,0,0,0,0};
            const float* wb2 = W2 + (size_t)oc * 576 + icq * 16 * 9;
#pragma unroll 1
            for (int ic16 = 0; ic16 < 16; ++ic16) {
                int ic = icq * 16 + ic16;
                const f4* ar = (const f4*)(sp1 + ic * 28);
                float av[28];
                *(f4*)&av[0]  = ar[0];
                *(f4*)&av[4]  = ar[1];
                *(f4*)&av[8]  = ar[2];
                *(f4*)&av[12] = ar[3];
                *(f4*)&av[16] = ar[4];
                *(f4*)&av[20] = ar[5];
                *(f4*)&av[24] = ar[6];
                const float* wi = wb2 + ic16 * 9;
                f4u w0 = *(const f4u*)wi;
                f4u w1 = *(const f4u*)(wi + 4);
                float wv[9] = { w0[0], w0[1], w0[2], w0[3], w1[0], w1[1], w1[2], w1[3], wi[8] };
#pragma unroll
                for (int py = 0; py < 3; ++py)
#pragma unroll
                    for (int px = 0; px < 3; ++px) {
                        int p9 = py * 3 + px;
#pragma unroll
                        for (int ky = 0; ky < 3; ++ky)
#pragma unroll
                            for (int kx = 0; kx < 3; ++kx)
                                a9[p9] = fmaf(wv[ky * 3 + kx],
                                              av[(py + ky) * 5 + (px + kx)], a9[p9]);
                    }
            }
#pragma unroll
            for (int p = 0; p < 9; ++p)
                cpart[((size_t)(t >> 6) * 64 + (t & 63)) * 11 + p] = a9[p];
        }
        __syncthreads();
        for (int i = t; i < 576; i += 256) {
            int pos = i >> 6, occ = i & 63;
            float s = cpart[((size_t)0 * 64 + occ) * 11 + pos]
                    + cpart[((size_t)1 * 64 + occ) * 11 + pos]
                    + cpart[((size_t)2 * 64 + occ) * 11 + pos]
                    + cpart[((size_t)3 * 64 + occ) * 11 + pos];
            sc2T[pos * 64 + occ] = fmaxf(s, 0.f);
        }
        __syncthreads();
    }

    // ---- W3 (256x64) + relu + avgpool3 3x3 -> 1 (broadcast f4 reads) ----
    float xfin;
    {
        float xw[9] = {0,0,0,0,0,0,0,0,0};
        const f4* wr = (const f4*)(W3 + (size_t)t * 64);
#pragma unroll 1
        for (int gg = 0; gg < 16; ++gg) {
            f4 wv4 = wr[gg];
#pragma unroll
            for (int p = 0; p < 9; ++p) {
                f4 c = *(const f4*)(sc2T + p * 64 + gg * 4);
                xw[p] = fmaf(wv4[0], c[0], xw[p]);
                xw[p] = fmaf(wv4[1], c[1], xw[p]);
                xw[p] = fmaf(wv4[2], c[2], xw[p]);
                xw[p] = fmaf(wv4[3], c[3], xw[p]);
            }
        }
        float s = 0.f;
#pragma unroll
        for (int p = 0; p < 9; ++p) s += fmaxf(xw[p], 0.f);
        xfin = s * (1.f / 9.f);
    }

    // ---- merged 5-way block reduction: ONE barrier ----
    float v0 = xfin * spr_w[t] + csum;
    float v1 = xfin * dpr_w[0 * 256 + t];
    float v2 = xfin * dpr_w[1 * 256 + t];
    float v3 = xfin * dpr_w[2 * 256 + t];
    float v4 = xfin * dpr_w[3 * 256 + t];
#pragma unroll
    for (int off = 32; off > 0; off >>= 1) {
        v0 += __shfl_xor(v0, off, 64);
        v1 += __shfl_xor(v1, off, 64);
        v2 += __shfl_xor(v2, off, 64);
        v3 += __shfl_xor(v3, off, 64);
        v4 += __shfl_xor(v4, off, 64);
    }
    if (l == 0) {
        red[w * 5 + 0] = v0; red[w * 5 + 1] = v1; red[w * 5 + 2] = v2;
        red[w * 5 + 3] = v3; red[w * 5 + 4] = v4;
    }
    __syncthreads();

    if (t == 0) {
        float r_s  = red[0] + red[5] + red[10] + red[15];
        float r_d0 = red[1] + red[6] + red[11] + red[16];
        float r_d1 = red[2] + red[7] + red[12] + red[17];
        float r_d2 = red[3] + red[8] + red[13] + red[18];
        float r_d3 = red[4] + red[9] + red[14] + red[19];

        ws[WS_SP + m] = r_s + spr_b[0] + scor_b[0];

        float d0 = r_d0 + dpr_b[0];
        float d1 = r_d1 + dpr_b[1];
        float d2 = fminf(r_d2 + dpr_b[2], 4.135166556742356f);
        float d3 = fminf(r_d3 + dpr_b[3], 4.135166556742356f);

        const float* pr = proposals + (size_t)m * 4;
        float x1p = pr[0], y1p = pr[1], x2p = pr[2], y2p = pr[3];
        float wd = x2p - x1p, hd = y2p - y1p;
        float cx = x1p + 0.5f * wd, cy = y1p + 0.5f * hd;
        float pcx = d0 * wd + cx, pcy = d1 * hd + cy;
        float pw = expf(d2) * wd, ph = expf(d3) * hd;
        float Wf = (float)image_size[1];
        float Hf = (float)image_size[0];
        out[(size_t)m * 4 + 0] = fminf(fmaxf(pcx - 0.5f * pw, 0.f), Wf);
        out[(size_t)m * 4 + 1] = fminf(fmaxf(pcy - 0.5f * ph, 0.f), Hf);
        out[(size_t)m * 4 + 2] = fminf(fmaxf(pcx + 0.5f * pw, 0.f), Wf);
        out[(size_t)m * 4 + 3] = fminf(fmaxf(pcy + 0.5f * ph, 0.f), Hf);
    }
}

// ---------------------------------------------------------------------------
// K3a: FC path as split-bf16 MFMA (big2). grid = 256, block = 256 (4 waves).
// Per block: h = relu(fc1_w @ xfc[512][16m]); score = sfc.relu(fc2_w @ h).
// B-frags in LDS, same verified lane convention; 288 MFMA replaces 3072
// broadcast ds_read_b128 (round-16 k_fc was LDS-issue-bound ~40 us).
// ---------------------------------------------------------------------------
__global__ __launch_bounds__(256) void k_fc_mfma(
    const float* __restrict__ fc1_b, const float* __restrict__ fc2_b,
    const float* __restrict__ sfc_w, const float* __restrict__ sfc_b,
    float* __restrict__ ws, float* __restrict__ out)
{
    __shared__ __align__(16) short xbh[16 * 512];   // 16 KB
    __shared__ __align__(16) short xbl[16 * 512];   // 16 KB
    __shared__ __align__(16) short hbh[16 * 256];   // 8 KB
    __shared__ __align__(16) short hbl[16 * 256];   // 8 KB
    __shared__ float sred[4][16];

    int t = threadIdx.x;
    int m0 = blockIdx.x * 16;
    int w = t >> 6, l = t & 63, cl = l & 15, g = l >> 4;

    // ---- stage xfc[512][16] -> bf16 hi/lo, layout [m][k] swizzled ----
    {
        int mi = t >> 4, kg = t & 15;      // thread: m row mi, k-chunk kg*32
        int mg = m0 + mi, b = mg >> 9;
        int swz = (mi & 7) << 3;
        const float* qsrc = ws + WS_QMEAN + (size_t)mg * 256;
        const float* ssrc = ws + WS_SMEAN + (size_t)b * 256;
#pragma unroll 1
        for (int kk = 0; kk < 32; ++kk) {
            int k = kg * 32 + kk;
            float v = (k < 256) ? qsrc[k] : ssrc[k - 256];
            unsigned short hh = bf16_rne(v);
            int idx = mi * 512 + (k ^ swz);
            xbh[idx] = (short)hh;
            xbl[idx] = (short)bf16_rne(v - bf16_to_f(hh));
        }
    }
    __syncthreads();

    // ---- fc1: [256x512] @ [512x16], wave w owns out-ch tiles w*4..w*4+3 ----
    const short* f1h = (const short*)(ws + WS_F1H);
    const short* f1l = (const short*)(ws + WS_F1L);
    f32x4 a1[4];
#pragma unroll
    for (int i = 0; i < 4; ++i) a1[i] = (f32x4)0.f;
    int bxor = (cl & 7) << 3;
#pragma unroll 1
    for (int ks = 0; ks < 16; ++ks) {
        int bidx = cl * 512 + ((ks * 32 + g * 8) ^ bxor);
        short8 bh = *(const short8*)&xbh[bidx];
        short8 bl = *(const short8*)&xbl[bidx];
#pragma unroll
        for (int i = 0; i < 4; ++i) {
            int mt = w * 4 + i;
            size_t off = ((size_t)(mt * 16 + ks) * 64 + l) * 8;
            short8 ah = *(const short8*)&f1h[off];
            short8 al = *(const short8*)&f1l[off];
            a1[i] = __builtin_amdgcn_mfma_f32_16x16x32_bf16(ah, bh, a1[i], 0, 0, 0);
            a1[i] = __builtin_amdgcn_mfma_f32_16x16x32_bf16(ah, bl, a1[i], 0, 0, 0);
            a1[i] = __builtin_amdgcn_mfma_f32_16x16x32_bf16(al, bh, a1[i], 0, 0, 0);
        }
    }
    // h = relu(a1 + b); write to hbh/hbl at [m=cl][ch] (swizzled by cl)
#pragma unroll
    for (int i = 0; i < 4; ++i) {
        int ch0 = (w * 4 + i) * 16 + g * 4;
#pragma unroll
        for (int q = 0; q < 4; ++q) {
            int ch = ch0 + q;
            float h = fmaxf(a1[i][q] + fc1_b[ch], 0.f);
            unsigned short hh = bf16_rne(h);
            int idx = cl * 256 + (ch ^ bxor);
            hbh[idx] = (short)hh;
            hbl[idx] = (short)bf16_rne(h - bf16_to_f(hh));
        }
    }
    __syncthreads();

    // ---- fc2: [256x256] @ [256x16] ----
    const short* f2h = (const short*)(ws + WS_F2H);
    const short* f2l = (const short*)(ws + WS_F2L);
    f32x4 a2[4];
#pragma unroll
    for (int i = 0; i < 4; ++i) a2[i] = (f32x4)0.f;
#pragma unroll 1
    for (int ks = 0; ks < 8; ++ks) {
        int bidx = cl * 256 + ((ks * 32 + g * 8) ^ bxor);
        short8 bh = *(const short8*)&hbh[bidx];
        short8 bl = *(const short8*)&hbl[bidx];
#pragma unroll
        for (int i = 0; i < 4; ++i) {
            int mt = w * 4 + i;
            size_t off = ((size_t)(mt * 8 + ks) * 64 + l) * 8;
            short8 ah = *(const short8*)&f2h[off];
            short8 al = *(const short8*)&f2l[off];
            a2[i] = __builtin_amdgcn_mfma_f32_16x16x32_bf16(ah, bh, a2[i], 0, 0, 0);
            a2[i] = __builtin_amdgcn_mfma_f32_16x16x32_bf16(ah, bl, a2[i], 0, 0, 0);
            a2[i] = __builtin_amdgcn_mfma_f32_16x16x32_bf16(al, bh, a2[i], 0, 0, 0);
        }
    }

    // val[m=cl] partial = sum over this thread's (ch) of sfc_w[ch]*relu(.)
    float p = 0.f;
#pragma unroll
    for (int i = 0; i < 4; ++i) {
        int ch0 = (w * 4 + i) * 16 + g * 4;
#pragma unroll
        for (int q = 0; q < 4; ++q) {
            int ch = ch0 + q;
            p += sfc_w[ch] * fmaxf(a2[i][q] + fc2_b[ch], 0.f);
        }
    }
    p += __shfl_xor(p, 16, 64);     // sum over g
    p += __shfl_xor(p, 32, 64);
    if (l < 16) sred[w][l] = p;
    __syncthreads();

    if (t < 16) {
        float r = sred[0][t] + sred[1][t] + sred[2][t] + sred[3][t];
        float tot = ws[WS_SP + m0 + t] + (r + sfc_b[0]);
        out[OUT_SCORES + m0 + t] = 1.0f / (1.0f + expf(-tot));
    }
}

// ---------------------------------------------------------------------------
// K3b: VALU FC fallback (round-16 version, passing). grid = 256, block = 256.
// ---------------------------------------------------------------------------
__global__ __launch_bounds__(256) void k_fc_valu(
    const float* __restrict__ fc1_w, const float* __restrict__ fc1_b,
    const float* __restrict__ fc2_w, const float* __restrict__ fc2_b,
    const float* __restrict__ sfc_w, const float* __restrict__ sfc_b,
    float* __restrict__ ws, float* __restrict__ out)
{
    __shared__ __align__(16) float sxfc[16][512];
    __shared__ __align__(16) float sh1[16][256];
    __shared__ float s_red[64];
    int t = threadIdx.x;
    int m0 = blockIdx.x * 16;
    int w = t >> 6, l = t & 63;

#pragma unroll
    for (int mi = 0; mi < 16; ++mi) {
        int mg = m0 + mi;
        int b = mg >> 9;
        sxfc[mi][t]       = ws[WS_QMEAN + (size_t)mg * 256 + t];
        sxfc[mi][256 + t] = ws[WS_SMEAN + (size_t)b * 256 + t];
    }
    __syncthreads();

    {
        const f4* wr = (const f4*)(fc1_w + t * 512);
        float acc[16];
#pragma unroll
        for (int mi = 0; mi < 16; ++mi) acc[mi] = 0.f;
#pragma unroll 1
        for (int k4 = 0; k4 < 128; ++k4) {
            f4 wv = wr[k4];
#pragma unroll
            for (int mi = 0; mi < 16; ++mi) {
                f4 x = ((const f4*)sxfc[mi])[k4];
                acc[mi] = fmaf(wv[0], x[0], acc[mi]);
                acc[mi] = fmaf(wv[1], x[1], acc[mi]);
                acc[mi] = fmaf(wv[2], x[2], acc[mi]);
                acc[mi] = fmaf(wv[3], x[3], acc[mi]);
            }
        }
        float bb = fc1_b[t];
#pragma unroll
        for (int mi = 0; mi < 16; ++mi) sh1[mi][t] = fmaxf(acc[mi] + bb, 0.f);
    }
    __syncthreads();

    float val[16];
    {
        const f4* wr = (const f4*)(fc2_w + t * 256);
        float acc[16];
#pragma unroll
        for (int mi = 0; mi < 16; ++mi) acc[mi] = 0.f;
#pragma unroll 1
        for (int k4 = 0; k4 < 64; ++k4) {
            f4 wv = wr[k4];
#pragma unroll
            for (int mi = 0; mi < 16; ++mi) {
                f4 x = ((const f4*)sh1[mi])[k4];
                acc[mi] = fmaf(wv[0], x[0], acc[mi]);
                acc[mi] = fmaf(wv[1], x[1], acc[mi]);
                acc[mi] = fmaf(wv[2], x[2], acc[mi]);
                acc[mi] = fmaf(wv[3], x[3], acc[mi]);
            }
        }
        float bb = fc2_b[t];
        float sw = sfc_w[t];
#pragma unroll
        for (int mi = 0; mi < 16; ++mi) val[mi] = sw * fmaxf(acc[mi] + bb, 0.f);
    }

#pragma unroll
    for (int mi = 0; mi < 16; ++mi) {
        float v = val[mi];
#pragma unroll
        for (int off = 32; off > 0; off >>= 1) v += __shfl_xor(v, off, 64);
        if (l == 0) s_red[w * 16 + mi] = v;
    }
    __syncthreads();

    if (t < 16) {
        float r = s_red[0 * 16 + t] + s_red[1 * 16 + t]
                + s_red[2 * 16 + t] + s_red[3 * 16 + t];
        float tot = ws[WS_SP + m0 + t] + (r + sfc_b[0]);
        out[OUT_SCORES + m0 + t] = 1.0f / (1.0f + expf(-tot));
    }
}

// ---------------------------------------------------------------------------
// K4: fused NMS (sort + IoU mask + greedy + scatter), all in LDS.
// grid = 8, block = 1024 (16 waves).
// ---------------------------------------------------------------------------
__global__ __launch_bounds__(1024) void k_nms(float* __restrict__ out)
{
    __shared__ float ssc[512];
    __shared__ __align__(16) float sbox[512 * 4];
    __shared__ float sarea[512];
    __shared__ int   sidx[512];
    __shared__ unsigned long long smask[512 * 8];

    int t = threadIdx.x, b = blockIdx.x;
    int wv = t >> 6, lane = t & 63;
    const float* sc_g = out + OUT_SCORES + (size_t)b * 512;

    if (t < 512) ssc[t] = sc_g[t];
    __syncthreads();

    if (t < 512) {
        float si = ssc[t];
        int r = 0;
        for (int j = 0; j < 512; ++j) {
            float sj = ssc[j];
            r += (int)((sj > si) || (sj == si && j < t));
        }
        f4 v = *(const f4*)(out + ((size_t)b * 512 + t) * 4);
        *(f4*)&sbox[r * 4] = v;
        sarea[r] = fmaxf(v[2] - v[0], 0.f) * fmaxf(v[3] - v[1], 0.f);
        sidx[r] = t;
    }
    __syncthreads();

#pragma unroll 1
    for (int k = 0; k < 32; ++k) {
        int i = wv * 32 + k;
        f4 bi = *(const f4*)&sbox[i * 4];
        float ai = sarea[i];
#pragma unroll
        for (int w8 = 0; w8 < 8; ++w8) {
            int j = w8 * 64 + lane;
            f4 bj = *(const f4*)&sbox[j * 4];
            float aj = sarea[j];
            float xx1 = fmaxf(bi[0], bj[0]), yy1 = fmaxf(bi[1], bj[1]);
            float xx2 = fminf(bi[2], bj[2]), yy2 = fminf(bi[3], bj[3]);
            float inter = fmaxf(xx2 - xx1, 0.f) * fmaxf(yy2 - yy1, 0.f);
            float iou = inter / fmaxf(ai + aj - inter, 1e-9f);
            bool sup = (iou > 0.5f) && (j > i);
            unsigned long long bal = __ballot(sup);
            if (lane == 0) smask[i * 8 + w8] = bal;
        }
    }
    __syncthreads();

    if (wv == 0) {
        unsigned long long kw = ~0ull;
        unsigned long long nxt = (lane < 8) ? smask[lane] : 0ull;
        for (int i = 0; i < 512; ++i) {
            unsigned long long cur = nxt;
            if (i < 511 && lane < 8) nxt = smask[(size_t)(i + 1) * 8 + lane];
            unsigned long long wi = __shfl(kw, i >> 6, 64);
            if ((wi >> (i & 63)) & 1ull) {
                if (lane < 8) kw &= ~cur;
            }
        }
        if (lane < 8) smask[lane] = kw;
    }
    __syncthreads();

    if (t < 512) {
        unsigned long long word = smask[t >> 6];
        out[OUT_KEEP + (size_t)b * 512 + sidx[t]] =
            ((word >> (t & 63)) & 1ull) ? 1.0f : 0.0f;
    }
}

// ---------------------------------------------------------------------------
extern "C" void kernel_launch(void* const* d_in, const int* in_sizes, int n_in,
                              void* d_out, int out_size, void* d_ws, size_t ws_size,
                              hipStream_t stream) {
    const float* bfq       = (const float*)d_in[0];
    const float* bfs       = (const float*)d_in[1];
    const float* proposals = (const float*)d_in[2];
    const int*   image_sz  = (const int*)d_in[3];
    const float* W1        = (const float*)d_in[4];
    const float* W2        = (const float*)d_in[5];
    const float* W3        = (const float*)d_in[6];
    const float* Wcor      = (const float*)d_in[7];
    const float* fc1_w     = (const float*)d_in[8];
    const float* fc1_b     = (const float*)d_in[9];
    const float* fc2_w     = (const float*)d_in[10];
    const float* fc2_b     = (const float*)d_in[11];
    const float* sfc_w     = (const float*)d_in[12];
    const float* sfc_b     = (const float*)d_in[13];
    const float* scor_w    = (const float*)d_in[14];
    const float* scor_b    = (const float*)d_in[15];
    const float* spr_w     = (const float*)d_in[16];
    const float* spr_b     = (const float*)d_in[17];
    const float* dpr_w     = (const float*)d_in[18];
    const float* dpr_b     = (const float*)d_in[19];
    float* out = (float*)d_out;
    float* ws  = (float*)d_ws;

    int big  = (ws_size >= WS_NEED_BIG  * sizeof(float)) ? 1 : 0;
    int big2 = (ws_size >= WS_NEED_BIG2 * sizeof(float)) ? 1 : 0;
    int grid_prep = big2 ? 218 : (big ? 122 : 104);

    k_prep<<<grid_prep, 256, 0, stream>>>(bfs, Wcor, W1, W2, fc1_w, fc2_w,
                                          ws, big, big2);
    k_heavy<<<NM, 256, 0, stream>>>(bfq, W2, W3,
                                    scor_w, scor_b, spr_w, spr_b,
                                    dpr_w, dpr_b, proposals, image_sz, ws, out, big);
    if (big2)
        k_fc_mfma<<<NM / 16, 256, 0, stream>>>(fc1_b, fc2_b, sfc_w, sfc_b, ws, out);
    else
        k_fc_valu<<<NM / 16, 256, 0, stream>>>(fc1_w, fc1_b, fc2_w, fc2_b,
                                               sfc_w, sfc_b, ws, out);
    k_nms<<<NB, 1024, 0, stream>>>(out);
}